// Round 14
// baseline (321.104 us; speedup 1.0000x reference)
//
#include <hip/hip_runtime.h>
#include <hip/hip_fp16.h>

// VGAE encoder forward.
// R14: k_bin write-front fix. R13 regressed k_bin to grid 1024 -> chunk 3125
// -> ~4 edges = 32B per (block,bucket) write front = half-line amplification.
// Fix: 512 blocks x 512 threads (chunk 6250 -> 8 edges = full 64B line per
// front) with 2x R12's TLP. Plus nontemporal stores for streamed-once binned
// writes (k_bin scatter + d23 sorted write-back). xw1/spmm pulls unchanged.
//
// Stages: memset bcur | k_bin | k_xw1 | k_spmm_d23 | k_spmm_out

#define SH    7              // rows per bucket = 128
#define BROWS 128
#define NBKT_MAX 800         // runtime nbkt = (N+127)>>7 = 782 for N=100000
#define CAP   4864           // bucket capacity; mean 4092, sigma~64 -> +12 sigma
#define LOFS_STRIDE (BROWS + 4)
#define BINB  512            // bin blocks (chunk 6250 -> full-line fronts)

__device__ __forceinline__ uint2 nt_load_edge(const uint2* p) {
    unsigned long long v =
        __builtin_nontemporal_load(reinterpret_cast<const unsigned long long*>(p));
    return make_uint2((unsigned)v, (unsigned)(v >> 32));
}
__device__ __forceinline__ void nt_store_edge(uint2* p, uint2 e) {
    unsigned long long v = (unsigned long long)e.x |
                           ((unsigned long long)e.y << 32);
    __builtin_nontemporal_store(v, reinterpret_cast<unsigned long long*>(p));
}

// Bin edges by bucket = row>>SH. Two passes per block: LDS hist, one global
// atomicAdd per (block,bucket) to reserve, then placed nt writes.
__global__ __launch_bounds__(512)
void k_bin(const int* __restrict__ er, const int* __restrict__ ec,
           const float* __restrict__ ev, int* __restrict__ bcur,
           uint2* __restrict__ binned, int E, int nbkt) {
    __shared__ int lhist[NBKT_MAX];
    __shared__ int lbase[NBKT_MAX];
    __shared__ int lrank[NBKT_MAX];
    const int chunk = (E + gridDim.x - 1) / gridDim.x;
    const int lo = blockIdx.x * chunk;
    const int hi = min(lo + chunk, E);
    for (int t = threadIdx.x; t < nbkt; t += 512) { lhist[t] = 0; lrank[t] = 0; }
    __syncthreads();
    for (int e = lo + threadIdx.x; e < hi; e += 512)
        atomicAdd(&lhist[__builtin_nontemporal_load(&er[e]) >> SH], 1);
    __syncthreads();
    for (int t = threadIdx.x; t < nbkt; t += 512) {
        int n = lhist[t];
        lbase[t] = n ? atomicAdd(&bcur[t], n) : 0;
    }
    __syncthreads();
    for (int e = lo + threadIdx.x; e < hi; e += 512) {
        int r = __builtin_nontemporal_load(&er[e]);
        int b = r >> SH;
        int pos = lbase[b] + atomicAdd(&lrank[b], 1);
        if (pos < CAP) {
            int   c = __builtin_nontemporal_load(&ec[e]);
            float v = __builtin_nontemporal_load(&ev[e]);
            unsigned pack = ((unsigned)(r & (BROWS - 1)) << 17) | (unsigned)c;
            nt_store_edge(&binned[(size_t)b * CAP + pos],
                          make_uint2(pack, __float_as_uint(v)));
        }
    }
}

// XW1 = X @ W1, output fp16. Wave-per-row; lane L owns k {4L..4L+3, 256+4L..}.
__global__ __launch_bounds__(256, 2)
void k_xw1(const float* __restrict__ X, const float* __restrict__ W1,
           __half* __restrict__ out, int N) {
    const int lane = threadIdx.x & 63;
    const int wave  = (blockIdx.x * blockDim.x + threadIdx.x) >> 6;
    const int nwave = (gridDim.x * blockDim.x) >> 6;

    float w[8][16];
#pragma unroll
    for (int j = 0; j < 4; ++j) {
#pragma unroll
        for (int h4 = 0; h4 < 4; ++h4) {
            float4 a = *reinterpret_cast<const float4*>(W1 + (lane * 4 + j) * 16 + h4 * 4);
            w[j][h4*4+0] = a.x; w[j][h4*4+1] = a.y; w[j][h4*4+2] = a.z; w[j][h4*4+3] = a.w;
            float4 b = *reinterpret_cast<const float4*>(W1 + (256 + lane * 4 + j) * 16 + h4 * 4);
            w[4+j][h4*4+0] = b.x; w[4+j][h4*4+1] = b.y; w[4+j][h4*4+2] = b.z; w[4+j][h4*4+3] = b.w;
        }
    }

    const int l4 = lane & 15;
    const int hrev = ((l4 & 1) << 3) | ((l4 & 2) << 1) | ((l4 & 4) >> 1) | ((l4 & 8) >> 3);

    const float4* X4 = reinterpret_cast<const float4*>(X);

    int row = wave;
    if (row >= N) return;
    float4 xa = X4[(size_t)row * 128 + lane];
    float4 xb = X4[(size_t)row * 128 + 64 + lane];

    for (; row < N; row += nwave) {
        int nrow = row + nwave;
        float4 na, nb;
        if (nrow < N) {
            na = X4[(size_t)nrow * 128 + lane];
            nb = X4[(size_t)nrow * 128 + 64 + lane];
        }

        float a[16];
#pragma unroll
        for (int h = 0; h < 16; ++h) {
            a[h] = xa.x * w[0][h] + xa.y * w[1][h] + xa.z * w[2][h] + xa.w * w[3][h]
                 + xb.x * w[4][h] + xb.y * w[5][h] + xb.z * w[6][h] + xb.w * w[7][h];
        }

#define XW1_STEP(m, half_)                                                 \
        {                                                                  \
            const bool hi_ = (lane & (m)) != 0;                            \
            _Pragma("unroll")                                              \
            for (int i = 0; i < (half_); ++i) {                            \
                float send = hi_ ? a[i] : a[(half_) + i];                  \
                float keep = hi_ ? a[(half_) + i] : a[i];                  \
                a[i] = keep + __shfl_xor(send, (m));                       \
            }                                                              \
        }
        XW1_STEP(1, 8)
        XW1_STEP(2, 4)
        XW1_STEP(4, 2)
        XW1_STEP(8, 1)
#undef XW1_STEP
        a[0] += __shfl_xor(a[0], 16);
        a[0] += __shfl_xor(a[0], 32);

        if (lane < 16) out[(size_t)row * 16 + hrev] = __float2half(a[0]);

        xa = na; xb = nb;
    }
}

// Bucket SpMM (sort + pull, fp16 H) + relu+[W2|W3] epilogue (fp16 M out).
// Persists sorted bucket (nt) + lofs for k_spmm_out.
__global__ __launch_bounds__(1024)
void k_spmm_d23(uint2* __restrict__ binned, const int* __restrict__ bcur,
                int* __restrict__ lofs_g, const __half* __restrict__ H,
                const float* __restrict__ W2, const float* __restrict__ W3,
                __half* __restrict__ M, int N) {
    __shared__ uint2 se[CAP];
    __shared__ int lhist[BROWS];
    __shared__ int lofs[BROWS + 1];
    __shared__ int lrank[BROWS];
    const int b   = blockIdx.x;
    const int tid = threadIdx.x;

    if (tid < BROWS) { lhist[tid] = 0; lrank[tid] = 0; }
    __syncthreads();

    const int cnt = min(bcur[b], CAP);
    const uint2* eb = binned + (size_t)b * CAP;

    uint2 st[5]; int slr[5];
#pragma unroll
    for (int it = 0; it < 5; ++it) {
        int j = tid + it * 1024;
        if (j < cnt) {
            uint2 e = nt_load_edge(&eb[j]);
            st[it] = e;
            slr[it] = (int)(e.x >> 17);
            atomicAdd(&lhist[slr[it]], 1);
        } else slr[it] = -1;
    }
    __syncthreads();

    if (tid < BROWS) lofs[tid + 1] = lhist[tid];
    if (tid == 0) lofs[0] = 0;
    __syncthreads();
    for (int off = 1; off < BROWS; off <<= 1) {
        int v = (tid < BROWS && tid >= off) ? lofs[tid + 1 - off] : 0;
        __syncthreads();
        if (tid < BROWS) lofs[tid + 1] += v;
        __syncthreads();
    }

#pragma unroll
    for (int it = 0; it < 5; ++it) {
        if (slr[it] >= 0) {
            int pos = lofs[slr[it]] + atomicAdd(&lrank[slr[it]], 1);
            se[pos] = st[it];
        }
    }
    __syncthreads();

    // persist sorted bucket + offsets for k_spmm_out
    uint2* wb = binned + (size_t)b * CAP;
#pragma unroll
    for (int it = 0; it < 5; ++it) {
        int j = tid + it * 1024;
        if (j < cnt) nt_store_edge(&wb[j], se[j]);
    }
    if (tid <= BROWS) lofs_g[b * LOFS_STRIDE + tid] = lofs[tid];

    // register pull (fp16 gather, L2-resident 3.2MB table)
    const int f = tid & 15;
    const int g = tid >> 4;
    float wcol[16];
    if (f < 7) {
#pragma unroll
        for (int k = 0; k < 16; ++k) wcol[k] = W2[k * 7 + f];
    } else if (f < 14) {
#pragma unroll
        for (int k = 0; k < 16; ++k) wcol[k] = W3[k * 7 + (f - 7)];
    } else {
#pragma unroll
        for (int k = 0; k < 16; ++k) wcol[k] = 0.f;
    }
    const int rbase = b << SH;
#pragma unroll
    for (int rr = 0; rr < BROWS; rr += 64) {
        const int lr = rr + g;
        const int beg = lofs[lr], end = lofs[lr + 1];
        float acc = 0.f;
        for (int j = beg; j < end; ++j) {
            uint2 e = se[j];                       // LDS broadcast in group
            acc += __uint_as_float(e.y) *
                   __half2float(H[(size_t)(e.x & 0x1FFFF) * 16 + f]);
        }
        float a = fmaxf(acc, 0.f);
        float o = 0.f;
#pragma unroll
        for (int k = 0; k < 16; ++k) o += __shfl(a, k, 16) * wcol[k];
        int row = rbase + lr;
        if (row < N) M[(size_t)row * 16 + f] = __float2half(o);
    }
}

// Bucket SpMM (pre-sorted: copy + pull, fp16 H) + reparameterization.
__global__ __launch_bounds__(1024)
void k_spmm_out(const uint2* __restrict__ binned, const int* __restrict__ bcur,
                const int* __restrict__ lofs_g, const __half* __restrict__ H,
                const float* __restrict__ eps, float* __restrict__ out, int N) {
    __shared__ uint2 se[CAP];
    __shared__ int lofs[BROWS + 1];
    const int b   = blockIdx.x;
    const int tid = threadIdx.x;

    if (tid <= BROWS) lofs[tid] = lofs_g[b * LOFS_STRIDE + tid];

    const int cnt = min(bcur[b], CAP);
    const uint2* eb = binned + (size_t)b * CAP;
#pragma unroll
    for (int it = 0; it < 5; ++it) {
        int j = tid + it * 1024;
        if (j < cnt) se[j] = nt_load_edge(&eb[j]);
    }
    __syncthreads();

    const int f = tid & 15;
    const int g = tid >> 4;
    const int rbase = b << SH;
#pragma unroll
    for (int rr = 0; rr < BROWS; rr += 64) {
        const int lr = rr + g;
        const int beg = lofs[lr], end = lofs[lr + 1];
        float acc = 0.f;
        for (int j = beg; j < end; ++j) {
            uint2 e = se[j];
            acc += __uint_as_float(e.y) *
                   __half2float(H[(size_t)(e.x & 0x1FFFF) * 16 + f]);
        }
        const int src = (f < 7) ? (f + 7) : f;
        float ls = __shfl(acc, src, 16);
        int row = rbase + lr;
        if (row < N && f < 7) {
            out[(size_t)row * 7 + f] = acc + eps[(size_t)row * 7 + f] * __expf(ls);
        }
    }
}

extern "C" void kernel_launch(void* const* d_in, const int* in_sizes, int n_in,
                              void* d_out, int out_size, void* d_ws, size_t ws_size,
                              hipStream_t stream) {
    const float* X   = (const float*)d_in[0];
    const int*   er  = (const int*)d_in[1];
    const int*   ec  = (const int*)d_in[2];
    const float* ev  = (const float*)d_in[3];
    const float* W1  = (const float*)d_in[4];
    const float* W2  = (const float*)d_in[5];
    const float* W3  = (const float*)d_in[6];
    const float* eps = (const float*)d_in[7];
    float* out = (float*)d_out;

    const int N    = in_sizes[0] / 512;
    const int E    = in_sizes[1];
    const int nbkt = (N + BROWS - 1) >> SH;   // 782 for N=100000 (<= NBKT_MAX)

    // workspace layout (halves first, then ints, then edge records)
    __half* XW1_h = (__half*)d_ws;                        // N*16 fp16 (3.2MB)
    __half* M23_h = XW1_h + (size_t)N * 16;               // N*16 fp16 (3.2MB)
    int*    bcur  = (int*)(M23_h + (size_t)N * 16);       // pad 1024 ints
    int*    lofs_g= bcur + 1024;                          // NBKT_MAX*LOFS_STRIDE
    uint2*  binned= (uint2*)(lofs_g + NBKT_MAX * LOFS_STRIDE); // nbkt*CAP*8B

    (void)hipMemsetAsync(bcur, 0, (size_t)nbkt * sizeof(int), stream);
    k_bin     <<<BINB, 512, 0, stream>>>(er, ec, ev, bcur, binned, E, nbkt);
    k_xw1     <<<2048, 256, 0, stream>>>(X, W1, XW1_h, N);
    k_spmm_d23<<<nbkt, 1024, 0, stream>>>(binned, bcur, lofs_g, XW1_h, W2, W3, M23_h, N);
    k_spmm_out<<<nbkt, 1024, 0, stream>>>(binned, bcur, lofs_g, M23_h, eps, out, N);
}

// Round 15
// 218.846 us; speedup vs baseline: 1.4673x; 1.4673x over previous
//
#include <hip/hip_runtime.h>
#include <hip/hip_fp16.h>

// VGAE encoder forward.
// R15: k_bin v3 — LDS-staged local counting sort. R14 proved write fronts
// are nbkt*blocks=400K (not nbkt) and temporally scattered -> no merging,
// WRITE stuck at ~115MB. Fix: per-block sort the 6250-edge chunk into a
// 50KB LDS buffer (reg stash 13/thread -> hist -> scan -> place), then
// flush linearly so consecutive threads write consecutive global addresses
// (full-line writes by construction). Rest of pipeline = R13/R14.
//
// Stages: memset bcur | k_bin | k_xw1 | k_spmm_d23 | k_spmm_out

#define SH    7              // rows per bucket = 128
#define BROWS 128
#define NBKT_MAX 800         // runtime nbkt = (N+127)>>7 = 782 for N=100000
#define CAP   4864           // bucket capacity; mean 4092 -> +12 sigma
#define LOFS_STRIDE (BROWS + 4)
#define BINB  512            // bin blocks; chunk = E/512 = 6250
#define BCHUNK 6272          // LDS staging capacity (>= chunk)
#define BSLOT 13             // ceil(6250/512) register stash slots

__device__ __forceinline__ uint2 nt_load_edge(const uint2* p) {
    unsigned long long v =
        __builtin_nontemporal_load(reinterpret_cast<const unsigned long long*>(p));
    return make_uint2((unsigned)v, (unsigned)(v >> 32));
}
__device__ __forceinline__ void nt_store_edge(uint2* p, uint2 e) {
    unsigned long long v = (unsigned long long)e.x |
                           ((unsigned long long)e.y << 32);
    __builtin_nontemporal_store(v, reinterpret_cast<unsigned long long*>(p));
}

// k_bin v3: per-block counting sort into LDS, then linear coalesced flush.
__global__ __launch_bounds__(512)
void k_bin(const int* __restrict__ er, const int* __restrict__ ec,
           const float* __restrict__ ev, int* __restrict__ bcur,
           uint2* __restrict__ binned, int E, int nbkt) {
    __shared__ uint2 buf[BCHUNK];                // 50.2 KB sorted stage
    __shared__ int lofs[NBKT_MAX + 1];           // inclusive-scan offsets
    __shared__ int lcnt[NBKT_MAX];               // hist, reused as place-rank
    __shared__ int gbase[NBKT_MAX];              // per-bucket global base
    const int tid = threadIdx.x;
    const int chunk = (E + BINB - 1) / BINB;
    const int lo = blockIdx.x * chunk;
    const int hi = min(lo + chunk, E);
    const int cnt_tile = hi - lo;

    for (int t = tid; t < nbkt; t += 512) lcnt[t] = 0;
    __syncthreads();

    // pass 1: load (nt), stash in regs, hist
    uint2 st[BSLOT]; int sb[BSLOT];
#pragma unroll
    for (int it = 0; it < BSLOT; ++it) {
        int e = lo + tid + it * 512;
        if (e < hi) {
            int r = __builtin_nontemporal_load(&er[e]);
            int c = __builtin_nontemporal_load(&ec[e]);
            float v = __builtin_nontemporal_load(&ev[e]);
            int b = r >> SH;
            st[it] = make_uint2(((unsigned)(r & (BROWS - 1)) << 17) | (unsigned)c,
                                __float_as_uint(v));
            sb[it] = b;
            atomicAdd(&lcnt[b], 1);
        } else sb[it] = -1;
    }
    __syncthreads();

    // inclusive scan lcnt -> lofs[1..nbkt], lofs[0] = 0 (Hillis-Steele,
    // 2 elements/thread, read-barrier-write-barrier)
    for (int t = tid; t < nbkt; t += 512) lofs[t + 1] = lcnt[t];
    if (tid == 0) lofs[0] = 0;
    __syncthreads();
    for (int off = 1; off < nbkt; off <<= 1) {
        int i0 = tid, i1 = tid + 512;
        int v0 = (i0 < nbkt && i0 >= off) ? lofs[i0 + 1 - off] : 0;
        int v1 = (i1 < nbkt && i1 >= off) ? lofs[i1 + 1 - off] : 0;
        __syncthreads();
        if (i0 < nbkt) lofs[i0 + 1] += v0;
        if (i1 < nbkt) lofs[i1 + 1] += v1;
        __syncthreads();
    }

    // reserve global ranges; reset lcnt for placement ranks
    for (int t = tid; t < nbkt; t += 512) {
        int n = lofs[t + 1] - lofs[t];
        gbase[t] = n ? atomicAdd(&bcur[t], n) : 0;
        lcnt[t] = 0;
    }
    __syncthreads();

    // pass 2: place stash into sorted LDS positions
#pragma unroll
    for (int it = 0; it < BSLOT; ++it) {
        if (sb[it] >= 0) {
            int pos = lofs[sb[it]] + atomicAdd(&lcnt[sb[it]], 1);
            buf[pos] = st[it];
        }
    }
    __syncthreads();

    // flush: consecutive threads -> consecutive global addresses per bucket
    for (int i = tid; i < cnt_tile; i += 512) {
        uint2 rec = buf[i];
        // bsearch: largest b with lofs[b] <= i
        int loB = 0, hiB = nbkt;
        while (hiB - loB > 1) {
            int mid = (loB + hiB) >> 1;
            if (lofs[mid] <= i) loB = mid; else hiB = mid;
        }
        int gpos = gbase[loB] + (i - lofs[loB]);
        if (gpos < CAP) binned[(size_t)loB * CAP + gpos] = rec;
    }
}

// XW1 = X @ W1, output fp16. Wave-per-row; lane L owns k {4L..4L+3, 256+4L..}.
__global__ __launch_bounds__(256, 2)
void k_xw1(const float* __restrict__ X, const float* __restrict__ W1,
           __half* __restrict__ out, int N) {
    const int lane = threadIdx.x & 63;
    const int wave  = (blockIdx.x * blockDim.x + threadIdx.x) >> 6;
    const int nwave = (gridDim.x * blockDim.x) >> 6;

    float w[8][16];
#pragma unroll
    for (int j = 0; j < 4; ++j) {
#pragma unroll
        for (int h4 = 0; h4 < 4; ++h4) {
            float4 a = *reinterpret_cast<const float4*>(W1 + (lane * 4 + j) * 16 + h4 * 4);
            w[j][h4*4+0] = a.x; w[j][h4*4+1] = a.y; w[j][h4*4+2] = a.z; w[j][h4*4+3] = a.w;
            float4 b = *reinterpret_cast<const float4*>(W1 + (256 + lane * 4 + j) * 16 + h4 * 4);
            w[4+j][h4*4+0] = b.x; w[4+j][h4*4+1] = b.y; w[4+j][h4*4+2] = b.z; w[4+j][h4*4+3] = b.w;
        }
    }

    const int l4 = lane & 15;
    const int hrev = ((l4 & 1) << 3) | ((l4 & 2) << 1) | ((l4 & 4) >> 1) | ((l4 & 8) >> 3);

    const float4* X4 = reinterpret_cast<const float4*>(X);

    int row = wave;
    if (row >= N) return;
    float4 xa = X4[(size_t)row * 128 + lane];
    float4 xb = X4[(size_t)row * 128 + 64 + lane];

    for (; row < N; row += nwave) {
        int nrow = row + nwave;
        float4 na, nb;
        if (nrow < N) {
            na = X4[(size_t)nrow * 128 + lane];
            nb = X4[(size_t)nrow * 128 + 64 + lane];
        }

        float a[16];
#pragma unroll
        for (int h = 0; h < 16; ++h) {
            a[h] = xa.x * w[0][h] + xa.y * w[1][h] + xa.z * w[2][h] + xa.w * w[3][h]
                 + xb.x * w[4][h] + xb.y * w[5][h] + xb.z * w[6][h] + xb.w * w[7][h];
        }

#define XW1_STEP(m, half_)                                                 \
        {                                                                  \
            const bool hi_ = (lane & (m)) != 0;                            \
            _Pragma("unroll")                                              \
            for (int i = 0; i < (half_); ++i) {                            \
                float send = hi_ ? a[i] : a[(half_) + i];                  \
                float keep = hi_ ? a[(half_) + i] : a[i];                  \
                a[i] = keep + __shfl_xor(send, (m));                       \
            }                                                              \
        }
        XW1_STEP(1, 8)
        XW1_STEP(2, 4)
        XW1_STEP(4, 2)
        XW1_STEP(8, 1)
#undef XW1_STEP
        a[0] += __shfl_xor(a[0], 16);
        a[0] += __shfl_xor(a[0], 32);

        if (lane < 16) out[(size_t)row * 16 + hrev] = __float2half(a[0]);

        xa = na; xb = nb;
    }
}

// Bucket SpMM (sort + pull, fp16 H) + relu+[W2|W3] epilogue (fp16 M out).
// Persists sorted bucket (nt) + lofs for k_spmm_out.
__global__ __launch_bounds__(1024)
void k_spmm_d23(uint2* __restrict__ binned, const int* __restrict__ bcur,
                int* __restrict__ lofs_g, const __half* __restrict__ H,
                const float* __restrict__ W2, const float* __restrict__ W3,
                __half* __restrict__ M, int N) {
    __shared__ uint2 se[CAP];
    __shared__ int lhist[BROWS];
    __shared__ int lofs[BROWS + 1];
    __shared__ int lrank[BROWS];
    const int b   = blockIdx.x;
    const int tid = threadIdx.x;

    if (tid < BROWS) { lhist[tid] = 0; lrank[tid] = 0; }
    __syncthreads();

    const int cnt = min(bcur[b], CAP);
    const uint2* eb = binned + (size_t)b * CAP;

    uint2 st[5]; int slr[5];
#pragma unroll
    for (int it = 0; it < 5; ++it) {
        int j = tid + it * 1024;
        if (j < cnt) {
            uint2 e = nt_load_edge(&eb[j]);
            st[it] = e;
            slr[it] = (int)(e.x >> 17);
            atomicAdd(&lhist[slr[it]], 1);
        } else slr[it] = -1;
    }
    __syncthreads();

    if (tid < BROWS) lofs[tid + 1] = lhist[tid];
    if (tid == 0) lofs[0] = 0;
    __syncthreads();
    for (int off = 1; off < BROWS; off <<= 1) {
        int v = (tid < BROWS && tid >= off) ? lofs[tid + 1 - off] : 0;
        __syncthreads();
        if (tid < BROWS) lofs[tid + 1] += v;
        __syncthreads();
    }

#pragma unroll
    for (int it = 0; it < 5; ++it) {
        if (slr[it] >= 0) {
            int pos = lofs[slr[it]] + atomicAdd(&lrank[slr[it]], 1);
            se[pos] = st[it];
        }
    }
    __syncthreads();

    // persist sorted bucket + offsets for k_spmm_out
    uint2* wb = binned + (size_t)b * CAP;
#pragma unroll
    for (int it = 0; it < 5; ++it) {
        int j = tid + it * 1024;
        if (j < cnt) nt_store_edge(&wb[j], se[j]);
    }
    if (tid <= BROWS) lofs_g[b * LOFS_STRIDE + tid] = lofs[tid];

    // register pull (fp16 gather, L2-resident 3.2MB table)
    const int f = tid & 15;
    const int g = tid >> 4;
    float wcol[16];
    if (f < 7) {
#pragma unroll
        for (int k = 0; k < 16; ++k) wcol[k] = W2[k * 7 + f];
    } else if (f < 14) {
#pragma unroll
        for (int k = 0; k < 16; ++k) wcol[k] = W3[k * 7 + (f - 7)];
    } else {
#pragma unroll
        for (int k = 0; k < 16; ++k) wcol[k] = 0.f;
    }
    const int rbase = b << SH;
#pragma unroll
    for (int rr = 0; rr < BROWS; rr += 64) {
        const int lr = rr + g;
        const int beg = lofs[lr], end = lofs[lr + 1];
        float acc = 0.f;
        for (int j = beg; j < end; ++j) {
            uint2 e = se[j];                       // LDS broadcast in group
            acc += __uint_as_float(e.y) *
                   __half2float(H[(size_t)(e.x & 0x1FFFF) * 16 + f]);
        }
        float a = fmaxf(acc, 0.f);
        float o = 0.f;
#pragma unroll
        for (int k = 0; k < 16; ++k) o += __shfl(a, k, 16) * wcol[k];
        int row = rbase + lr;
        if (row < N) M[(size_t)row * 16 + f] = __float2half(o);
    }
}

// Bucket SpMM (pre-sorted: copy + pull, fp16 H) + reparameterization.
__global__ __launch_bounds__(1024)
void k_spmm_out(const uint2* __restrict__ binned, const int* __restrict__ bcur,
                const int* __restrict__ lofs_g, const __half* __restrict__ H,
                const float* __restrict__ eps, float* __restrict__ out, int N) {
    __shared__ uint2 se[CAP];
    __shared__ int lofs[BROWS + 1];
    const int b   = blockIdx.x;
    const int tid = threadIdx.x;

    if (tid <= BROWS) lofs[tid] = lofs_g[b * LOFS_STRIDE + tid];

    const int cnt = min(bcur[b], CAP);
    const uint2* eb = binned + (size_t)b * CAP;
#pragma unroll
    for (int it = 0; it < 5; ++it) {
        int j = tid + it * 1024;
        if (j < cnt) se[j] = nt_load_edge(&eb[j]);
    }
    __syncthreads();

    const int f = tid & 15;
    const int g = tid >> 4;
    const int rbase = b << SH;
#pragma unroll
    for (int rr = 0; rr < BROWS; rr += 64) {
        const int lr = rr + g;
        const int beg = lofs[lr], end = lofs[lr + 1];
        float acc = 0.f;
        for (int j = beg; j < end; ++j) {
            uint2 e = se[j];
            acc += __uint_as_float(e.y) *
                   __half2float(H[(size_t)(e.x & 0x1FFFF) * 16 + f]);
        }
        const int src = (f < 7) ? (f + 7) : f;
        float ls = __shfl(acc, src, 16);
        int row = rbase + lr;
        if (row < N && f < 7) {
            out[(size_t)row * 7 + f] = acc + eps[(size_t)row * 7 + f] * __expf(ls);
        }
    }
}

extern "C" void kernel_launch(void* const* d_in, const int* in_sizes, int n_in,
                              void* d_out, int out_size, void* d_ws, size_t ws_size,
                              hipStream_t stream) {
    const float* X   = (const float*)d_in[0];
    const int*   er  = (const int*)d_in[1];
    const int*   ec  = (const int*)d_in[2];
    const float* ev  = (const float*)d_in[3];
    const float* W1  = (const float*)d_in[4];
    const float* W2  = (const float*)d_in[5];
    const float* W3  = (const float*)d_in[6];
    const float* eps = (const float*)d_in[7];
    float* out = (float*)d_out;

    const int N    = in_sizes[0] / 512;
    const int E    = in_sizes[1];
    const int nbkt = (N + BROWS - 1) >> SH;   // 782 for N=100000 (<= NBKT_MAX)

    // workspace layout (halves first, then ints, then edge records)
    __half* XW1_h = (__half*)d_ws;                        // N*16 fp16 (3.2MB)
    __half* M23_h = XW1_h + (size_t)N * 16;               // N*16 fp16 (3.2MB)
    int*    bcur  = (int*)(M23_h + (size_t)N * 16);       // pad 1024 ints
    int*    lofs_g= bcur + 1024;                          // NBKT_MAX*LOFS_STRIDE
    uint2*  binned= (uint2*)(lofs_g + NBKT_MAX * LOFS_STRIDE); // nbkt*CAP*8B

    (void)hipMemsetAsync(bcur, 0, (size_t)nbkt * sizeof(int), stream);
    k_bin     <<<BINB, 512, 0, stream>>>(er, ec, ev, bcur, binned, E, nbkt);
    k_xw1     <<<2048, 256, 0, stream>>>(X, W1, XW1_h, N);
    k_spmm_d23<<<nbkt, 1024, 0, stream>>>(binned, bcur, lofs_g, XW1_h, W2, W3, M23_h, N);
    k_spmm_out<<<nbkt, 1024, 0, stream>>>(binned, bcur, lofs_g, M23_h, eps, out, N);
}

// Round 16
// 191.346 us; speedup vs baseline: 1.6781x; 1.1437x over previous
//
#include <hip/hip_runtime.h>
#include <hip/hip_fp16.h>

// VGAE encoder forward.
// R16: MLP fix for the pull loops. The spmm inner loop was a serial chain
// {LDS edge -> L2 gather (~200cy) -> FMA} x ~64 per group, 1 outstanding
// load per wave -> latency-bound (VALUBusy 2-6% in every spmm profile).
// Unroll by 4 with 4 independent accumulators -> 4 gathers in flight ->
// ~4x MLP on the critical path. Applied to both spmm kernels; everything
// else identical to R15.
//
// Stages: memset bcur | k_bin | k_xw1 | k_spmm_d23 | k_spmm_out

#define SH    7              // rows per bucket = 128
#define BROWS 128
#define NBKT_MAX 800         // runtime nbkt = (N+127)>>7 = 782 for N=100000
#define CAP   4864           // bucket capacity; mean 4092 -> +12 sigma
#define LOFS_STRIDE (BROWS + 4)
#define BINB  512            // bin blocks; chunk = E/512 = 6250
#define BCHUNK 6272          // LDS staging capacity (>= chunk)
#define BSLOT 13             // ceil(6250/512) register stash slots

__device__ __forceinline__ uint2 nt_load_edge(const uint2* p) {
    unsigned long long v =
        __builtin_nontemporal_load(reinterpret_cast<const unsigned long long*>(p));
    return make_uint2((unsigned)v, (unsigned)(v >> 32));
}
__device__ __forceinline__ void nt_store_edge(uint2* p, uint2 e) {
    unsigned long long v = (unsigned long long)e.x |
                           ((unsigned long long)e.y << 32);
    __builtin_nontemporal_store(v, reinterpret_cast<unsigned long long*>(p));
}

// k_bin v3: per-block counting sort into LDS, then linear coalesced flush.
__global__ __launch_bounds__(512)
void k_bin(const int* __restrict__ er, const int* __restrict__ ec,
           const float* __restrict__ ev, int* __restrict__ bcur,
           uint2* __restrict__ binned, int E, int nbkt) {
    __shared__ uint2 buf[BCHUNK];                // 50.2 KB sorted stage
    __shared__ int lofs[NBKT_MAX + 1];           // inclusive-scan offsets
    __shared__ int lcnt[NBKT_MAX];               // hist, reused as place-rank
    __shared__ int gbase[NBKT_MAX];              // per-bucket global base
    const int tid = threadIdx.x;
    const int chunk = (E + BINB - 1) / BINB;
    const int lo = blockIdx.x * chunk;
    const int hi = min(lo + chunk, E);
    const int cnt_tile = hi - lo;

    for (int t = tid; t < nbkt; t += 512) lcnt[t] = 0;
    __syncthreads();

    // pass 1: load (nt), stash in regs, hist
    uint2 st[BSLOT]; int sb[BSLOT];
#pragma unroll
    for (int it = 0; it < BSLOT; ++it) {
        int e = lo + tid + it * 512;
        if (e < hi) {
            int r = __builtin_nontemporal_load(&er[e]);
            int c = __builtin_nontemporal_load(&ec[e]);
            float v = __builtin_nontemporal_load(&ev[e]);
            int b = r >> SH;
            st[it] = make_uint2(((unsigned)(r & (BROWS - 1)) << 17) | (unsigned)c,
                                __float_as_uint(v));
            sb[it] = b;
            atomicAdd(&lcnt[b], 1);
        } else sb[it] = -1;
    }
    __syncthreads();

    // inclusive scan lcnt -> lofs[1..nbkt], lofs[0] = 0
    for (int t = tid; t < nbkt; t += 512) lofs[t + 1] = lcnt[t];
    if (tid == 0) lofs[0] = 0;
    __syncthreads();
    for (int off = 1; off < nbkt; off <<= 1) {
        int i0 = tid, i1 = tid + 512;
        int v0 = (i0 < nbkt && i0 >= off) ? lofs[i0 + 1 - off] : 0;
        int v1 = (i1 < nbkt && i1 >= off) ? lofs[i1 + 1 - off] : 0;
        __syncthreads();
        if (i0 < nbkt) lofs[i0 + 1] += v0;
        if (i1 < nbkt) lofs[i1 + 1] += v1;
        __syncthreads();
    }

    // reserve global ranges; reset lcnt for placement ranks
    for (int t = tid; t < nbkt; t += 512) {
        int n = lofs[t + 1] - lofs[t];
        gbase[t] = n ? atomicAdd(&bcur[t], n) : 0;
        lcnt[t] = 0;
    }
    __syncthreads();

    // pass 2: place stash into sorted LDS positions
#pragma unroll
    for (int it = 0; it < BSLOT; ++it) {
        if (sb[it] >= 0) {
            int pos = lofs[sb[it]] + atomicAdd(&lcnt[sb[it]], 1);
            buf[pos] = st[it];
        }
    }
    __syncthreads();

    // flush: consecutive threads -> consecutive global addresses per bucket
    for (int i = tid; i < cnt_tile; i += 512) {
        uint2 rec = buf[i];
        int loB = 0, hiB = nbkt;
        while (hiB - loB > 1) {
            int mid = (loB + hiB) >> 1;
            if (lofs[mid] <= i) loB = mid; else hiB = mid;
        }
        int gpos = gbase[loB] + (i - lofs[loB]);
        if (gpos < CAP) binned[(size_t)loB * CAP + gpos] = rec;
    }
}

// XW1 = X @ W1, output fp16. Wave-per-row; lane L owns k {4L..4L+3, 256+4L..}.
__global__ __launch_bounds__(256, 2)
void k_xw1(const float* __restrict__ X, const float* __restrict__ W1,
           __half* __restrict__ out, int N) {
    const int lane = threadIdx.x & 63;
    const int wave  = (blockIdx.x * blockDim.x + threadIdx.x) >> 6;
    const int nwave = (gridDim.x * blockDim.x) >> 6;

    float w[8][16];
#pragma unroll
    for (int j = 0; j < 4; ++j) {
#pragma unroll
        for (int h4 = 0; h4 < 4; ++h4) {
            float4 a = *reinterpret_cast<const float4*>(W1 + (lane * 4 + j) * 16 + h4 * 4);
            w[j][h4*4+0] = a.x; w[j][h4*4+1] = a.y; w[j][h4*4+2] = a.z; w[j][h4*4+3] = a.w;
            float4 b = *reinterpret_cast<const float4*>(W1 + (256 + lane * 4 + j) * 16 + h4 * 4);
            w[4+j][h4*4+0] = b.x; w[4+j][h4*4+1] = b.y; w[4+j][h4*4+2] = b.z; w[4+j][h4*4+3] = b.w;
        }
    }

    const int l4 = lane & 15;
    const int hrev = ((l4 & 1) << 3) | ((l4 & 2) << 1) | ((l4 & 4) >> 1) | ((l4 & 8) >> 3);

    const float4* X4 = reinterpret_cast<const float4*>(X);

    int row = wave;
    if (row >= N) return;
    float4 xa = X4[(size_t)row * 128 + lane];
    float4 xb = X4[(size_t)row * 128 + 64 + lane];

    for (; row < N; row += nwave) {
        int nrow = row + nwave;
        float4 na, nb;
        if (nrow < N) {
            na = X4[(size_t)nrow * 128 + lane];
            nb = X4[(size_t)nrow * 128 + 64 + lane];
        }

        float a[16];
#pragma unroll
        for (int h = 0; h < 16; ++h) {
            a[h] = xa.x * w[0][h] + xa.y * w[1][h] + xa.z * w[2][h] + xa.w * w[3][h]
                 + xb.x * w[4][h] + xb.y * w[5][h] + xb.z * w[6][h] + xb.w * w[7][h];
        }

#define XW1_STEP(m, half_)                                                 \
        {                                                                  \
            const bool hi_ = (lane & (m)) != 0;                            \
            _Pragma("unroll")                                              \
            for (int i = 0; i < (half_); ++i) {                            \
                float send = hi_ ? a[i] : a[(half_) + i];                  \
                float keep = hi_ ? a[(half_) + i] : a[i];                  \
                a[i] = keep + __shfl_xor(send, (m));                       \
            }                                                              \
        }
        XW1_STEP(1, 8)
        XW1_STEP(2, 4)
        XW1_STEP(4, 2)
        XW1_STEP(8, 1)
#undef XW1_STEP
        a[0] += __shfl_xor(a[0], 16);
        a[0] += __shfl_xor(a[0], 32);

        if (lane < 16) out[(size_t)row * 16 + hrev] = __float2half(a[0]);

        xa = na; xb = nb;
    }
}

// 4-way-unrolled pull body (4 independent gathers in flight).
__device__ __forceinline__ float pull_row(const uint2* __restrict__ se,
                                          int beg, int end,
                                          const __half* __restrict__ H, int f) {
    float a0 = 0.f, a1 = 0.f, a2 = 0.f, a3 = 0.f;
    int j = beg;
    for (; j + 4 <= end; j += 4) {
        uint2 e0 = se[j], e1 = se[j + 1], e2 = se[j + 2], e3 = se[j + 3];
        float h0 = __half2float(H[(size_t)(e0.x & 0x1FFFF) * 16 + f]);
        float h1 = __half2float(H[(size_t)(e1.x & 0x1FFFF) * 16 + f]);
        float h2 = __half2float(H[(size_t)(e2.x & 0x1FFFF) * 16 + f]);
        float h3 = __half2float(H[(size_t)(e3.x & 0x1FFFF) * 16 + f]);
        a0 += __uint_as_float(e0.y) * h0;
        a1 += __uint_as_float(e1.y) * h1;
        a2 += __uint_as_float(e2.y) * h2;
        a3 += __uint_as_float(e3.y) * h3;
    }
    for (; j < end; ++j) {
        uint2 e = se[j];
        a0 += __uint_as_float(e.y) *
              __half2float(H[(size_t)(e.x & 0x1FFFF) * 16 + f]);
    }
    return (a0 + a1) + (a2 + a3);
}

// Bucket SpMM (sort + pull, fp16 H) + relu+[W2|W3] epilogue (fp16 M out).
// Persists sorted bucket (nt) + lofs for k_spmm_out.
__global__ __launch_bounds__(1024)
void k_spmm_d23(uint2* __restrict__ binned, const int* __restrict__ bcur,
                int* __restrict__ lofs_g, const __half* __restrict__ H,
                const float* __restrict__ W2, const float* __restrict__ W3,
                __half* __restrict__ M, int N) {
    __shared__ uint2 se[CAP];
    __shared__ int lhist[BROWS];
    __shared__ int lofs[BROWS + 1];
    __shared__ int lrank[BROWS];
    const int b   = blockIdx.x;
    const int tid = threadIdx.x;

    if (tid < BROWS) { lhist[tid] = 0; lrank[tid] = 0; }
    __syncthreads();

    const int cnt = min(bcur[b], CAP);
    const uint2* eb = binned + (size_t)b * CAP;

    uint2 st[5]; int slr[5];
#pragma unroll
    for (int it = 0; it < 5; ++it) {
        int j = tid + it * 1024;
        if (j < cnt) {
            uint2 e = nt_load_edge(&eb[j]);
            st[it] = e;
            slr[it] = (int)(e.x >> 17);
            atomicAdd(&lhist[slr[it]], 1);
        } else slr[it] = -1;
    }
    __syncthreads();

    if (tid < BROWS) lofs[tid + 1] = lhist[tid];
    if (tid == 0) lofs[0] = 0;
    __syncthreads();
    for (int off = 1; off < BROWS; off <<= 1) {
        int v = (tid < BROWS && tid >= off) ? lofs[tid + 1 - off] : 0;
        __syncthreads();
        if (tid < BROWS) lofs[tid + 1] += v;
        __syncthreads();
    }

#pragma unroll
    for (int it = 0; it < 5; ++it) {
        if (slr[it] >= 0) {
            int pos = lofs[slr[it]] + atomicAdd(&lrank[slr[it]], 1);
            se[pos] = st[it];
        }
    }
    __syncthreads();

    // persist sorted bucket + offsets for k_spmm_out
    uint2* wb = binned + (size_t)b * CAP;
#pragma unroll
    for (int it = 0; it < 5; ++it) {
        int j = tid + it * 1024;
        if (j < cnt) nt_store_edge(&wb[j], se[j]);
    }
    if (tid <= BROWS) lofs_g[b * LOFS_STRIDE + tid] = lofs[tid];

    // register pull (fp16 gather, L2-resident table), 4-deep MLP
    const int f = tid & 15;
    const int g = tid >> 4;
    float wcol[16];
    if (f < 7) {
#pragma unroll
        for (int k = 0; k < 16; ++k) wcol[k] = W2[k * 7 + f];
    } else if (f < 14) {
#pragma unroll
        for (int k = 0; k < 16; ++k) wcol[k] = W3[k * 7 + (f - 7)];
    } else {
#pragma unroll
        for (int k = 0; k < 16; ++k) wcol[k] = 0.f;
    }
    const int rbase = b << SH;
#pragma unroll
    for (int rr = 0; rr < BROWS; rr += 64) {
        const int lr = rr + g;
        float acc = pull_row(se, lofs[lr], lofs[lr + 1], H, f);
        float a = fmaxf(acc, 0.f);
        float o = 0.f;
#pragma unroll
        for (int k = 0; k < 16; ++k) o += __shfl(a, k, 16) * wcol[k];
        int row = rbase + lr;
        if (row < N) M[(size_t)row * 16 + f] = __float2half(o);
    }
}

// Bucket SpMM (pre-sorted: copy + pull, fp16 H) + reparameterization.
__global__ __launch_bounds__(1024)
void k_spmm_out(const uint2* __restrict__ binned, const int* __restrict__ bcur,
                const int* __restrict__ lofs_g, const __half* __restrict__ H,
                const float* __restrict__ eps, float* __restrict__ out, int N) {
    __shared__ uint2 se[CAP];
    __shared__ int lofs[BROWS + 1];
    const int b   = blockIdx.x;
    const int tid = threadIdx.x;

    if (tid <= BROWS) lofs[tid] = lofs_g[b * LOFS_STRIDE + tid];

    const int cnt = min(bcur[b], CAP);
    const uint2* eb = binned + (size_t)b * CAP;
#pragma unroll
    for (int it = 0; it < 5; ++it) {
        int j = tid + it * 1024;
        if (j < cnt) se[j] = nt_load_edge(&eb[j]);
    }
    __syncthreads();

    const int f = tid & 15;
    const int g = tid >> 4;
    const int rbase = b << SH;
#pragma unroll
    for (int rr = 0; rr < BROWS; rr += 64) {
        const int lr = rr + g;
        float acc = pull_row(se, lofs[lr], lofs[lr + 1], H, f);
        const int src = (f < 7) ? (f + 7) : f;
        float ls = __shfl(acc, src, 16);
        int row = rbase + lr;
        if (row < N && f < 7) {
            out[(size_t)row * 7 + f] = acc + eps[(size_t)row * 7 + f] * __expf(ls);
        }
    }
}

extern "C" void kernel_launch(void* const* d_in, const int* in_sizes, int n_in,
                              void* d_out, int out_size, void* d_ws, size_t ws_size,
                              hipStream_t stream) {
    const float* X   = (const float*)d_in[0];
    const int*   er  = (const int*)d_in[1];
    const int*   ec  = (const int*)d_in[2];
    const float* ev  = (const float*)d_in[3];
    const float* W1  = (const float*)d_in[4];
    const float* W2  = (const float*)d_in[5];
    const float* W3  = (const float*)d_in[6];
    const float* eps = (const float*)d_in[7];
    float* out = (float*)d_out;

    const int N    = in_sizes[0] / 512;
    const int E    = in_sizes[1];
    const int nbkt = (N + BROWS - 1) >> SH;   // 782 for N=100000 (<= NBKT_MAX)

    // workspace layout (halves first, then ints, then edge records)
    __half* XW1_h = (__half*)d_ws;                        // N*16 fp16 (3.2MB)
    __half* M23_h = XW1_h + (size_t)N * 16;               // N*16 fp16 (3.2MB)
    int*    bcur  = (int*)(M23_h + (size_t)N * 16);       // pad 1024 ints
    int*    lofs_g= bcur + 1024;                          // NBKT_MAX*LOFS_STRIDE
    uint2*  binned= (uint2*)(lofs_g + NBKT_MAX * LOFS_STRIDE); // nbkt*CAP*8B

    (void)hipMemsetAsync(bcur, 0, (size_t)nbkt * sizeof(int), stream);
    k_bin     <<<BINB, 512, 0, stream>>>(er, ec, ev, bcur, binned, E, nbkt);
    k_xw1     <<<2048, 256, 0, stream>>>(X, W1, XW1_h, N);
    k_spmm_d23<<<nbkt, 1024, 0, stream>>>(binned, bcur, lofs_g, XW1_h, W2, W3, M23_h, N);
    k_spmm_out<<<nbkt, 1024, 0, stream>>>(binned, bcur, lofs_g, M23_h, eps, out, N);
}

// Round 17
// 183.783 us; speedup vs baseline: 1.7472x; 1.0412x over previous
//
#include <hip/hip_runtime.h>
#include <hip/hip_fp16.h>

// VGAE encoder forward.
// R17: two independent chain-shorteners.
//  (1) half2 pulls: 8 lanes/row (lane f gathers __half2 = features 2f,2f+1).
//      1024-thr block -> 128 groups = 1 row/group: per-group serial edge
//      chain halves vs 16-lane/2-row scheme. Epilogues in 8-lane shfl form;
//      M23 stored as __half2.
//  (2) k_xw1 row-pair pipeline: each wave does rows (2w,2w+1) with next-pair
//      prefetch -> 2x in-flight HBM bytes per wave.
// Everything else identical to R16.
//
// Stages: memset bcur | k_bin | k_xw1 | k_spmm_d23 | k_spmm_out

#define SH    7              // rows per bucket = 128
#define BROWS 128
#define NBKT_MAX 800         // runtime nbkt = (N+127)>>7 = 782 for N=100000
#define CAP   4864           // bucket capacity; mean 4092 -> +12 sigma
#define LOFS_STRIDE (BROWS + 4)
#define BINB  512            // bin blocks; chunk = E/512 = 6250
#define BCHUNK 6272          // LDS staging capacity (>= chunk)
#define BSLOT 13             // ceil(6250/512) register stash slots

__device__ __forceinline__ uint2 nt_load_edge(const uint2* p) {
    unsigned long long v =
        __builtin_nontemporal_load(reinterpret_cast<const unsigned long long*>(p));
    return make_uint2((unsigned)v, (unsigned)(v >> 32));
}
__device__ __forceinline__ void nt_store_edge(uint2* p, uint2 e) {
    unsigned long long v = (unsigned long long)e.x |
                           ((unsigned long long)e.y << 32);
    __builtin_nontemporal_store(v, reinterpret_cast<unsigned long long*>(p));
}

// k_bin v3: per-block counting sort into LDS, then linear coalesced flush.
__global__ __launch_bounds__(512)
void k_bin(const int* __restrict__ er, const int* __restrict__ ec,
           const float* __restrict__ ev, int* __restrict__ bcur,
           uint2* __restrict__ binned, int E, int nbkt) {
    __shared__ uint2 buf[BCHUNK];                // 50.2 KB sorted stage
    __shared__ int lofs[NBKT_MAX + 1];
    __shared__ int lcnt[NBKT_MAX];
    __shared__ int gbase[NBKT_MAX];
    const int tid = threadIdx.x;
    const int chunk = (E + BINB - 1) / BINB;
    const int lo = blockIdx.x * chunk;
    const int hi = min(lo + chunk, E);
    const int cnt_tile = hi - lo;

    for (int t = tid; t < nbkt; t += 512) lcnt[t] = 0;
    __syncthreads();

    uint2 st[BSLOT]; int sb[BSLOT];
#pragma unroll
    for (int it = 0; it < BSLOT; ++it) {
        int e = lo + tid + it * 512;
        if (e < hi) {
            int r = __builtin_nontemporal_load(&er[e]);
            int c = __builtin_nontemporal_load(&ec[e]);
            float v = __builtin_nontemporal_load(&ev[e]);
            int b = r >> SH;
            st[it] = make_uint2(((unsigned)(r & (BROWS - 1)) << 17) | (unsigned)c,
                                __float_as_uint(v));
            sb[it] = b;
            atomicAdd(&lcnt[b], 1);
        } else sb[it] = -1;
    }
    __syncthreads();

    for (int t = tid; t < nbkt; t += 512) lofs[t + 1] = lcnt[t];
    if (tid == 0) lofs[0] = 0;
    __syncthreads();
    for (int off = 1; off < nbkt; off <<= 1) {
        int i0 = tid, i1 = tid + 512;
        int v0 = (i0 < nbkt && i0 >= off) ? lofs[i0 + 1 - off] : 0;
        int v1 = (i1 < nbkt && i1 >= off) ? lofs[i1 + 1 - off] : 0;
        __syncthreads();
        if (i0 < nbkt) lofs[i0 + 1] += v0;
        if (i1 < nbkt) lofs[i1 + 1] += v1;
        __syncthreads();
    }

    for (int t = tid; t < nbkt; t += 512) {
        int n = lofs[t + 1] - lofs[t];
        gbase[t] = n ? atomicAdd(&bcur[t], n) : 0;
        lcnt[t] = 0;
    }
    __syncthreads();

#pragma unroll
    for (int it = 0; it < BSLOT; ++it) {
        if (sb[it] >= 0) {
            int pos = lofs[sb[it]] + atomicAdd(&lcnt[sb[it]], 1);
            buf[pos] = st[it];
        }
    }
    __syncthreads();

    for (int i = tid; i < cnt_tile; i += 512) {
        uint2 rec = buf[i];
        int loB = 0, hiB = nbkt;
        while (hiB - loB > 1) {
            int mid = (loB + hiB) >> 1;
            if (lofs[mid] <= i) loB = mid; else hiB = mid;
        }
        int gpos = gbase[loB] + (i - lofs[loB]);
        if (gpos < CAP) binned[(size_t)loB * CAP + gpos] = rec;
    }
}

// XW1 = X @ W1, fp16 out. Row-pair per wave with next-pair prefetch.
__global__ __launch_bounds__(256, 2)
void k_xw1(const float* __restrict__ X, const float* __restrict__ W1,
           __half* __restrict__ out, int N) {
    const int lane = threadIdx.x & 63;
    const int wave  = (blockIdx.x * blockDim.x + threadIdx.x) >> 6;
    const int nwave = (gridDim.x * blockDim.x) >> 6;
    const int step  = nwave * 2;

    float w[8][16];
#pragma unroll
    for (int j = 0; j < 4; ++j) {
#pragma unroll
        for (int h4 = 0; h4 < 4; ++h4) {
            float4 a = *reinterpret_cast<const float4*>(W1 + (lane * 4 + j) * 16 + h4 * 4);
            w[j][h4*4+0] = a.x; w[j][h4*4+1] = a.y; w[j][h4*4+2] = a.z; w[j][h4*4+3] = a.w;
            float4 b = *reinterpret_cast<const float4*>(W1 + (256 + lane * 4 + j) * 16 + h4 * 4);
            w[4+j][h4*4+0] = b.x; w[4+j][h4*4+1] = b.y; w[4+j][h4*4+2] = b.z; w[4+j][h4*4+3] = b.w;
        }
    }

    const int l4 = lane & 15;
    const int hrev = ((l4 & 1) << 3) | ((l4 & 2) << 1) | ((l4 & 4) >> 1) | ((l4 & 8) >> 3);

    const float4* X4 = reinterpret_cast<const float4*>(X);

    int row = wave * 2;
    if (row >= N) return;
    int r1 = min(row + 1, N - 1);
    float4 xa0 = X4[(size_t)row * 128 + lane];
    float4 xb0 = X4[(size_t)row * 128 + 64 + lane];
    float4 xa1 = X4[(size_t)r1 * 128 + lane];
    float4 xb1 = X4[(size_t)r1 * 128 + 64 + lane];

    for (; row < N; row += step) {
        int nr = row + step;
        float4 na0, nb0, na1, nb1;
        if (nr < N) {
            int nr1 = min(nr + 1, N - 1);
            na0 = X4[(size_t)nr * 128 + lane];
            nb0 = X4[(size_t)nr * 128 + 64 + lane];
            na1 = X4[(size_t)nr1 * 128 + lane];
            nb1 = X4[(size_t)nr1 * 128 + 64 + lane];
        }

        float a0[16], a1[16];
#pragma unroll
        for (int h = 0; h < 16; ++h) {
            a0[h] = xa0.x * w[0][h] + xa0.y * w[1][h] + xa0.z * w[2][h] + xa0.w * w[3][h]
                  + xb0.x * w[4][h] + xb0.y * w[5][h] + xb0.z * w[6][h] + xb0.w * w[7][h];
            a1[h] = xa1.x * w[0][h] + xa1.y * w[1][h] + xa1.z * w[2][h] + xa1.w * w[3][h]
                  + xb1.x * w[4][h] + xb1.y * w[5][h] + xb1.z * w[6][h] + xb1.w * w[7][h];
        }

#define XW1_STEP(arr, m, half_)                                            \
        {                                                                  \
            const bool hi_ = (lane & (m)) != 0;                            \
            _Pragma("unroll")                                              \
            for (int i = 0; i < (half_); ++i) {                            \
                float send = hi_ ? arr[i] : arr[(half_) + i];              \
                float keep = hi_ ? arr[(half_) + i] : arr[i];              \
                arr[i] = keep + __shfl_xor(send, (m));                     \
            }                                                              \
        }
        XW1_STEP(a0, 1, 8) XW1_STEP(a0, 2, 4) XW1_STEP(a0, 4, 2) XW1_STEP(a0, 8, 1)
        a0[0] += __shfl_xor(a0[0], 16);
        a0[0] += __shfl_xor(a0[0], 32);
        XW1_STEP(a1, 1, 8) XW1_STEP(a1, 2, 4) XW1_STEP(a1, 4, 2) XW1_STEP(a1, 8, 1)
        a1[0] += __shfl_xor(a1[0], 16);
        a1[0] += __shfl_xor(a1[0], 32);
#undef XW1_STEP

        if (lane < 16) {
            out[(size_t)row * 16 + hrev] = __float2half(a0[0]);
            if (row + 1 < N) out[(size_t)(row + 1) * 16 + hrev] = __float2half(a1[0]);
        }

        xa0 = na0; xb0 = nb0; xa1 = na1; xb1 = nb1;
    }
}

// half2 pull body: lane f gathers features {2f,2f+1}; 4-deep MLP.
__device__ __forceinline__ float2 pull_row2(const uint2* __restrict__ se,
                                            int beg, int end,
                                            const __half2* __restrict__ H2, int f) {
    float x0=0.f,y0=0.f,x1=0.f,y1=0.f,x2=0.f,y2=0.f,x3=0.f,y3=0.f;
    int j = beg;
    for (; j + 4 <= end; j += 4) {
        uint2 e0 = se[j], e1 = se[j+1], e2 = se[j+2], e3 = se[j+3];
        float2 h0 = __half22float2(H2[(size_t)(e0.x & 0x1FFFF) * 8 + f]);
        float2 h1 = __half22float2(H2[(size_t)(e1.x & 0x1FFFF) * 8 + f]);
        float2 h2 = __half22float2(H2[(size_t)(e2.x & 0x1FFFF) * 8 + f]);
        float2 h3 = __half22float2(H2[(size_t)(e3.x & 0x1FFFF) * 8 + f]);
        float v0 = __uint_as_float(e0.y), v1 = __uint_as_float(e1.y);
        float v2 = __uint_as_float(e2.y), v3 = __uint_as_float(e3.y);
        x0 += v0 * h0.x; y0 += v0 * h0.y;
        x1 += v1 * h1.x; y1 += v1 * h1.y;
        x2 += v2 * h2.x; y2 += v2 * h2.y;
        x3 += v3 * h3.x; y3 += v3 * h3.y;
    }
    for (; j < end; ++j) {
        uint2 e = se[j];
        float2 h = __half22float2(H2[(size_t)(e.x & 0x1FFFF) * 8 + f]);
        float v = __uint_as_float(e.y);
        x0 += v * h.x; y0 += v * h.y;
    }
    return make_float2((x0 + x1) + (x2 + x3), (y0 + y1) + (y2 + y3));
}

// Bucket SpMM (sort + half2 pull) + relu+[W2|W3] epilogue (half2 M out).
__global__ __launch_bounds__(1024)
void k_spmm_d23(uint2* __restrict__ binned, const int* __restrict__ bcur,
                int* __restrict__ lofs_g, const __half2* __restrict__ H2,
                const float* __restrict__ W2, const float* __restrict__ W3,
                __half2* __restrict__ M2, int N) {
    __shared__ uint2 se[CAP];
    __shared__ int lhist[BROWS];
    __shared__ int lofs[BROWS + 1];
    __shared__ int lrank[BROWS];
    const int b   = blockIdx.x;
    const int tid = threadIdx.x;

    if (tid < BROWS) { lhist[tid] = 0; lrank[tid] = 0; }
    __syncthreads();

    const int cnt = min(bcur[b], CAP);
    const uint2* eb = binned + (size_t)b * CAP;

    uint2 st[5]; int slr[5];
#pragma unroll
    for (int it = 0; it < 5; ++it) {
        int j = tid + it * 1024;
        if (j < cnt) {
            uint2 e = nt_load_edge(&eb[j]);
            st[it] = e;
            slr[it] = (int)(e.x >> 17);
            atomicAdd(&lhist[slr[it]], 1);
        } else slr[it] = -1;
    }
    __syncthreads();

    if (tid < BROWS) lofs[tid + 1] = lhist[tid];
    if (tid == 0) lofs[0] = 0;
    __syncthreads();
    for (int off = 1; off < BROWS; off <<= 1) {
        int v = (tid < BROWS && tid >= off) ? lofs[tid + 1 - off] : 0;
        __syncthreads();
        if (tid < BROWS) lofs[tid + 1] += v;
        __syncthreads();
    }

#pragma unroll
    for (int it = 0; it < 5; ++it) {
        if (slr[it] >= 0) {
            int pos = lofs[slr[it]] + atomicAdd(&lrank[slr[it]], 1);
            se[pos] = st[it];
        }
    }
    __syncthreads();

    // persist sorted bucket + offsets for k_spmm_out
    uint2* wb = binned + (size_t)b * CAP;
#pragma unroll
    for (int it = 0; it < 5; ++it) {
        int j = tid + it * 1024;
        if (j < cnt) nt_store_edge(&wb[j], se[j]);
    }
    if (tid <= BROWS) lofs_g[b * LOFS_STRIDE + tid] = lofs[tid];

    // half2 pull: 128 groups of 8 lanes, group = local row
    const int f = tid & 7;      // feature pair {2f, 2f+1}
    const int g = tid >> 3;     // local row
    const int j0 = 2 * f, j1 = 2 * f + 1;
    float wA[16], wB[16];
#pragma unroll
    for (int k = 0; k < 16; ++k) {
        wA[k] = (j0 < 7) ? W2[k * 7 + j0] : (j0 < 14 ? W3[k * 7 + (j0 - 7)] : 0.f);
        wB[k] = (j1 < 7) ? W2[k * 7 + j1] : (j1 < 14 ? W3[k * 7 + (j1 - 7)] : 0.f);
    }
    float2 acc = pull_row2(se, lofs[g], lofs[g + 1], H2, f);
    float ax = fmaxf(acc.x, 0.f), ay = fmaxf(acc.y, 0.f);
    float oA = 0.f, oB = 0.f;
#pragma unroll
    for (int s = 0; s < 8; ++s) {
        float rx = __shfl(ax, s, 8);
        float ry = __shfl(ay, s, 8);
        oA += rx * wA[2*s] + ry * wA[2*s + 1];
        oB += rx * wB[2*s] + ry * wB[2*s + 1];
    }
    int row = (b << SH) + g;
    if (row < N) M2[(size_t)row * 8 + f] = __floats2half2_rn(oA, oB);
}

// Bucket SpMM (pre-sorted: copy + half2 pull) + reparameterization.
__global__ __launch_bounds__(1024)
void k_spmm_out(const uint2* __restrict__ binned, const int* __restrict__ bcur,
                const int* __restrict__ lofs_g, const __half2* __restrict__ H2,
                const float* __restrict__ eps, float* __restrict__ out, int N) {
    __shared__ uint2 se[CAP];
    __shared__ int lofs[BROWS + 1];
    const int b   = blockIdx.x;
    const int tid = threadIdx.x;

    if (tid <= BROWS) lofs[tid] = lofs_g[b * LOFS_STRIDE + tid];

    const int cnt = min(bcur[b], CAP);
    const uint2* eb = binned + (size_t)b * CAP;
#pragma unroll
    for (int it = 0; it < 5; ++it) {
        int j = tid + it * 1024;
        if (j < cnt) se[j] = nt_load_edge(&eb[j]);
    }
    __syncthreads();

    const int f = tid & 7;
    const int g = tid >> 3;
    float2 acc = pull_row2(se, lofs[g], lofs[g + 1], H2, f);
    float ax = acc.x, ay = acc.y;

    // zm = feature f, ls = feature f+7 (features live at lane j>>1, comp j&1)
    float zx = __shfl(ax, f >> 1, 8), zy = __shfl(ay, f >> 1, 8);
    float zm = (f & 1) ? zy : zx;
    int s = f + 7;
    float lx = __shfl(ax, s >> 1, 8), ly = __shfl(ay, s >> 1, 8);
    float ls = (s & 1) ? ly : lx;

    int row = (b << SH) + g;
    if (row < N && f < 7) {
        out[(size_t)row * 7 + f] = zm + eps[(size_t)row * 7 + f] * __expf(ls);
    }
}

extern "C" void kernel_launch(void* const* d_in, const int* in_sizes, int n_in,
                              void* d_out, int out_size, void* d_ws, size_t ws_size,
                              hipStream_t stream) {
    const float* X   = (const float*)d_in[0];
    const int*   er  = (const int*)d_in[1];
    const int*   ec  = (const int*)d_in[2];
    const float* ev  = (const float*)d_in[3];
    const float* W1  = (const float*)d_in[4];
    const float* W2  = (const float*)d_in[5];
    const float* W3  = (const float*)d_in[6];
    const float* eps = (const float*)d_in[7];
    float* out = (float*)d_out;

    const int N    = in_sizes[0] / 512;
    const int E    = in_sizes[1];
    const int nbkt = (N + BROWS - 1) >> SH;   // 782 for N=100000 (<= NBKT_MAX)

    // workspace layout (halves first, then ints, then edge records)
    __half* XW1_h = (__half*)d_ws;                        // N*16 fp16 (3.2MB)
    __half* M23_h = XW1_h + (size_t)N * 16;               // N*16 fp16 (3.2MB)
    int*    bcur  = (int*)(M23_h + (size_t)N * 16);       // pad 1024 ints
    int*    lofs_g= bcur + 1024;                          // NBKT_MAX*LOFS_STRIDE
    uint2*  binned= (uint2*)(lofs_g + NBKT_MAX * LOFS_STRIDE); // nbkt*CAP*8B

    (void)hipMemsetAsync(bcur, 0, (size_t)nbkt * sizeof(int), stream);
    k_bin     <<<BINB, 512, 0, stream>>>(er, ec, ev, bcur, binned, E, nbkt);
    k_xw1     <<<2048, 256, 0, stream>>>(X, W1, XW1_h, N);
    k_spmm_d23<<<nbkt, 1024, 0, stream>>>(binned, bcur, lofs_g,
                                          (const __half2*)XW1_h, W2, W3,
                                          (__half2*)M23_h, N);
    k_spmm_out<<<nbkt, 1024, 0, stream>>>(binned, bcur, lofs_g,
                                          (const __half2*)M23_h, eps, out, N);
}

// Round 18
// 177.186 us; speedup vs baseline: 1.8122x; 1.0372x over previous
//
#include <hip/hip_runtime.h>
#include <hip/hip_fp16.h>

// VGAE encoder forward.
// R18: sort-machinery chain removal.
//  (1) k_bin flush: the per-edge ~10-step LDS bsearch (130 serial LDS loads
//      per thread) replaced by a uint16 bid[] array written during the place
//      pass -- flush reads the bucket id directly.
//  (2) k_spmm_d23 hist: 4-way replicated lhist (tid&3) -> 4x less LDS-atomic
//      serialization on the 128 hot counters; merged at scan-prep.
// Everything else identical to R17.
//
// Stages: memset bcur | k_bin | k_xw1 | k_spmm_d23 | k_spmm_out

#define SH    7              // rows per bucket = 128
#define BROWS 128
#define NBKT_MAX 800         // runtime nbkt = (N+127)>>7 = 782 for N=100000
#define CAP   4864           // bucket capacity; mean 4092 -> +12 sigma
#define LOFS_STRIDE (BROWS + 4)
#define BINB  512            // bin blocks; chunk = E/512 = 6250
#define BCHUNK 6272          // LDS staging capacity (>= chunk)
#define BSLOT 13             // ceil(6250/512) register stash slots

__device__ __forceinline__ uint2 nt_load_edge(const uint2* p) {
    unsigned long long v =
        __builtin_nontemporal_load(reinterpret_cast<const unsigned long long*>(p));
    return make_uint2((unsigned)v, (unsigned)(v >> 32));
}
__device__ __forceinline__ void nt_store_edge(uint2* p, uint2 e) {
    unsigned long long v = (unsigned long long)e.x |
                           ((unsigned long long)e.y << 32);
    __builtin_nontemporal_store(v, reinterpret_cast<unsigned long long*>(p));
}

// k_bin v4: per-block counting sort into LDS + bid[] id array, linear flush.
__global__ __launch_bounds__(512)
void k_bin(const int* __restrict__ er, const int* __restrict__ ec,
           const float* __restrict__ ev, int* __restrict__ bcur,
           uint2* __restrict__ binned, int E, int nbkt) {
    __shared__ uint2 buf[BCHUNK];                // 50.2 KB sorted stage
    __shared__ unsigned short bid[BCHUNK];       // 12.5 KB bucket ids
    __shared__ int lofs[NBKT_MAX + 1];
    __shared__ int lcnt[NBKT_MAX];
    __shared__ int gbase[NBKT_MAX];
    const int tid = threadIdx.x;
    const int chunk = (E + BINB - 1) / BINB;
    const int lo = blockIdx.x * chunk;
    const int hi = min(lo + chunk, E);
    const int cnt_tile = hi - lo;

    for (int t = tid; t < nbkt; t += 512) lcnt[t] = 0;
    __syncthreads();

    // pass 1: load (nt), stash in regs, hist
    uint2 st[BSLOT]; int sb[BSLOT];
#pragma unroll
    for (int it = 0; it < BSLOT; ++it) {
        int e = lo + tid + it * 512;
        if (e < hi) {
            int r = __builtin_nontemporal_load(&er[e]);
            int c = __builtin_nontemporal_load(&ec[e]);
            float v = __builtin_nontemporal_load(&ev[e]);
            int b = r >> SH;
            st[it] = make_uint2(((unsigned)(r & (BROWS - 1)) << 17) | (unsigned)c,
                                __float_as_uint(v));
            sb[it] = b;
            atomicAdd(&lcnt[b], 1);
        } else sb[it] = -1;
    }
    __syncthreads();

    // inclusive scan lcnt -> lofs[1..nbkt], lofs[0] = 0
    for (int t = tid; t < nbkt; t += 512) lofs[t + 1] = lcnt[t];
    if (tid == 0) lofs[0] = 0;
    __syncthreads();
    for (int off = 1; off < nbkt; off <<= 1) {
        int i0 = tid, i1 = tid + 512;
        int v0 = (i0 < nbkt && i0 >= off) ? lofs[i0 + 1 - off] : 0;
        int v1 = (i1 < nbkt && i1 >= off) ? lofs[i1 + 1 - off] : 0;
        __syncthreads();
        if (i0 < nbkt) lofs[i0 + 1] += v0;
        if (i1 < nbkt) lofs[i1 + 1] += v1;
        __syncthreads();
    }

    // reserve global ranges; reset lcnt for placement ranks
    for (int t = tid; t < nbkt; t += 512) {
        int n = lofs[t + 1] - lofs[t];
        gbase[t] = n ? atomicAdd(&bcur[t], n) : 0;
        lcnt[t] = 0;
    }
    __syncthreads();

    // pass 2: place stash into sorted LDS positions (+ record bucket id)
#pragma unroll
    for (int it = 0; it < BSLOT; ++it) {
        if (sb[it] >= 0) {
            int pos = lofs[sb[it]] + atomicAdd(&lcnt[sb[it]], 1);
            buf[pos] = st[it];
            bid[pos] = (unsigned short)sb[it];
        }
    }
    __syncthreads();

    // flush: consecutive threads -> consecutive global addresses per bucket
    for (int i = tid; i < cnt_tile; i += 512) {
        uint2 rec = buf[i];
        int b = bid[i];
        int gpos = gbase[b] + (i - lofs[b]);
        if (gpos < CAP) binned[(size_t)b * CAP + gpos] = rec;
    }
}

// XW1 = X @ W1, fp16 out. Row-pair per wave with next-pair prefetch.
__global__ __launch_bounds__(256, 2)
void k_xw1(const float* __restrict__ X, const float* __restrict__ W1,
           __half* __restrict__ out, int N) {
    const int lane = threadIdx.x & 63;
    const int wave  = (blockIdx.x * blockDim.x + threadIdx.x) >> 6;
    const int nwave = (gridDim.x * blockDim.x) >> 6;
    const int step  = nwave * 2;

    float w[8][16];
#pragma unroll
    for (int j = 0; j < 4; ++j) {
#pragma unroll
        for (int h4 = 0; h4 < 4; ++h4) {
            float4 a = *reinterpret_cast<const float4*>(W1 + (lane * 4 + j) * 16 + h4 * 4);
            w[j][h4*4+0] = a.x; w[j][h4*4+1] = a.y; w[j][h4*4+2] = a.z; w[j][h4*4+3] = a.w;
            float4 b = *reinterpret_cast<const float4*>(W1 + (256 + lane * 4 + j) * 16 + h4 * 4);
            w[4+j][h4*4+0] = b.x; w[4+j][h4*4+1] = b.y; w[4+j][h4*4+2] = b.z; w[4+j][h4*4+3] = b.w;
        }
    }

    const int l4 = lane & 15;
    const int hrev = ((l4 & 1) << 3) | ((l4 & 2) << 1) | ((l4 & 4) >> 1) | ((l4 & 8) >> 3);

    const float4* X4 = reinterpret_cast<const float4*>(X);

    int row = wave * 2;
    if (row >= N) return;
    int r1 = min(row + 1, N - 1);
    float4 xa0 = X4[(size_t)row * 128 + lane];
    float4 xb0 = X4[(size_t)row * 128 + 64 + lane];
    float4 xa1 = X4[(size_t)r1 * 128 + lane];
    float4 xb1 = X4[(size_t)r1 * 128 + 64 + lane];

    for (; row < N; row += step) {
        int nr = row + step;
        float4 na0, nb0, na1, nb1;
        if (nr < N) {
            int nr1 = min(nr + 1, N - 1);
            na0 = X4[(size_t)nr * 128 + lane];
            nb0 = X4[(size_t)nr * 128 + 64 + lane];
            na1 = X4[(size_t)nr1 * 128 + lane];
            nb1 = X4[(size_t)nr1 * 128 + 64 + lane];
        }

        float a0[16], a1[16];
#pragma unroll
        for (int h = 0; h < 16; ++h) {
            a0[h] = xa0.x * w[0][h] + xa0.y * w[1][h] + xa0.z * w[2][h] + xa0.w * w[3][h]
                  + xb0.x * w[4][h] + xb0.y * w[5][h] + xb0.z * w[6][h] + xb0.w * w[7][h];
            a1[h] = xa1.x * w[0][h] + xa1.y * w[1][h] + xa1.z * w[2][h] + xa1.w * w[3][h]
                  + xb1.x * w[4][h] + xb1.y * w[5][h] + xb1.z * w[6][h] + xb1.w * w[7][h];
        }

#define XW1_STEP(arr, m, half_)                                            \
        {                                                                  \
            const bool hi_ = (lane & (m)) != 0;                            \
            _Pragma("unroll")                                              \
            for (int i = 0; i < (half_); ++i) {                            \
                float send = hi_ ? arr[i] : arr[(half_) + i];              \
                float keep = hi_ ? arr[(half_) + i] : arr[i];              \
                arr[i] = keep + __shfl_xor(send, (m));                     \
            }                                                              \
        }
        XW1_STEP(a0, 1, 8) XW1_STEP(a0, 2, 4) XW1_STEP(a0, 4, 2) XW1_STEP(a0, 8, 1)
        a0[0] += __shfl_xor(a0[0], 16);
        a0[0] += __shfl_xor(a0[0], 32);
        XW1_STEP(a1, 1, 8) XW1_STEP(a1, 2, 4) XW1_STEP(a1, 4, 2) XW1_STEP(a1, 8, 1)
        a1[0] += __shfl_xor(a1[0], 16);
        a1[0] += __shfl_xor(a1[0], 32);
#undef XW1_STEP

        if (lane < 16) {
            out[(size_t)row * 16 + hrev] = __float2half(a0[0]);
            if (row + 1 < N) out[(size_t)(row + 1) * 16 + hrev] = __float2half(a1[0]);
        }

        xa0 = na0; xb0 = nb0; xa1 = na1; xb1 = nb1;
    }
}

// half2 pull body: lane f gathers features {2f,2f+1}; 4-deep MLP.
__device__ __forceinline__ float2 pull_row2(const uint2* __restrict__ se,
                                            int beg, int end,
                                            const __half2* __restrict__ H2, int f) {
    float x0=0.f,y0=0.f,x1=0.f,y1=0.f,x2=0.f,y2=0.f,x3=0.f,y3=0.f;
    int j = beg;
    for (; j + 4 <= end; j += 4) {
        uint2 e0 = se[j], e1 = se[j+1], e2 = se[j+2], e3 = se[j+3];
        float2 h0 = __half22float2(H2[(size_t)(e0.x & 0x1FFFF) * 8 + f]);
        float2 h1 = __half22float2(H2[(size_t)(e1.x & 0x1FFFF) * 8 + f]);
        float2 h2 = __half22float2(H2[(size_t)(e2.x & 0x1FFFF) * 8 + f]);
        float2 h3 = __half22float2(H2[(size_t)(e3.x & 0x1FFFF) * 8 + f]);
        float v0 = __uint_as_float(e0.y), v1 = __uint_as_float(e1.y);
        float v2 = __uint_as_float(e2.y), v3 = __uint_as_float(e3.y);
        x0 += v0 * h0.x; y0 += v0 * h0.y;
        x1 += v1 * h1.x; y1 += v1 * h1.y;
        x2 += v2 * h2.x; y2 += v2 * h2.y;
        x3 += v3 * h3.x; y3 += v3 * h3.y;
    }
    for (; j < end; ++j) {
        uint2 e = se[j];
        float2 h = __half22float2(H2[(size_t)(e.x & 0x1FFFF) * 8 + f]);
        float v = __uint_as_float(e.y);
        x0 += v * h.x; y0 += v * h.y;
    }
    return make_float2((x0 + x1) + (x2 + x3), (y0 + y1) + (y2 + y3));
}

// Bucket SpMM (sort + half2 pull) + relu+[W2|W3] epilogue (half2 M out).
__global__ __launch_bounds__(1024)
void k_spmm_d23(uint2* __restrict__ binned, const int* __restrict__ bcur,
                int* __restrict__ lofs_g, const __half2* __restrict__ H2,
                const float* __restrict__ W2, const float* __restrict__ W3,
                __half2* __restrict__ M2, int N) {
    __shared__ uint2 se[CAP];
    __shared__ int lhist[4][BROWS];     // 4-way replicated hist
    __shared__ int lofs[BROWS + 1];
    __shared__ int lrank[BROWS];
    const int b   = blockIdx.x;
    const int tid = threadIdx.x;
    const int rep = tid & 3;

    if (tid < BROWS) {
        lhist[0][tid] = 0; lhist[1][tid] = 0;
        lhist[2][tid] = 0; lhist[3][tid] = 0;
        lrank[tid] = 0;
    }
    __syncthreads();

    const int cnt = min(bcur[b], CAP);
    const uint2* eb = binned + (size_t)b * CAP;

    uint2 st[5]; int slr[5];
#pragma unroll
    for (int it = 0; it < 5; ++it) {
        int j = tid + it * 1024;
        if (j < cnt) {
            uint2 e = nt_load_edge(&eb[j]);
            st[it] = e;
            slr[it] = (int)(e.x >> 17);
            atomicAdd(&lhist[rep][slr[it]], 1);
        } else slr[it] = -1;
    }
    __syncthreads();

    if (tid < BROWS)
        lofs[tid + 1] = lhist[0][tid] + lhist[1][tid] + lhist[2][tid] + lhist[3][tid];
    if (tid == 0) lofs[0] = 0;
    __syncthreads();
    for (int off = 1; off < BROWS; off <<= 1) {
        int v = (tid < BROWS && tid >= off) ? lofs[tid + 1 - off] : 0;
        __syncthreads();
        if (tid < BROWS) lofs[tid + 1] += v;
        __syncthreads();
    }

#pragma unroll
    for (int it = 0; it < 5; ++it) {
        if (slr[it] >= 0) {
            int pos = lofs[slr[it]] + atomicAdd(&lrank[slr[it]], 1);
            se[pos] = st[it];
        }
    }
    __syncthreads();

    // persist sorted bucket + offsets for k_spmm_out
    uint2* wb = binned + (size_t)b * CAP;
#pragma unroll
    for (int it = 0; it < 5; ++it) {
        int j = tid + it * 1024;
        if (j < cnt) nt_store_edge(&wb[j], se[j]);
    }
    if (tid <= BROWS) lofs_g[b * LOFS_STRIDE + tid] = lofs[tid];

    // half2 pull: 128 groups of 8 lanes, group = local row
    const int f = tid & 7;      // feature pair {2f, 2f+1}
    const int g = tid >> 3;     // local row
    const int j0 = 2 * f, j1 = 2 * f + 1;
    float wA[16], wB[16];
#pragma unroll
    for (int k = 0; k < 16; ++k) {
        wA[k] = (j0 < 7) ? W2[k * 7 + j0] : (j0 < 14 ? W3[k * 7 + (j0 - 7)] : 0.f);
        wB[k] = (j1 < 7) ? W2[k * 7 + j1] : (j1 < 14 ? W3[k * 7 + (j1 - 7)] : 0.f);
    }
    float2 acc = pull_row2(se, lofs[g], lofs[g + 1], H2, f);
    float ax = fmaxf(acc.x, 0.f), ay = fmaxf(acc.y, 0.f);
    float oA = 0.f, oB = 0.f;
#pragma unroll
    for (int s = 0; s < 8; ++s) {
        float rx = __shfl(ax, s, 8);
        float ry = __shfl(ay, s, 8);
        oA += rx * wA[2*s] + ry * wA[2*s + 1];
        oB += rx * wB[2*s] + ry * wB[2*s + 1];
    }
    int row = (b << SH) + g;
    if (row < N) M2[(size_t)row * 8 + f] = __floats2half2_rn(oA, oB);
}

// Bucket SpMM (pre-sorted: copy + half2 pull) + reparameterization.
__global__ __launch_bounds__(1024)
void k_spmm_out(const uint2* __restrict__ binned, const int* __restrict__ bcur,
                const int* __restrict__ lofs_g, const __half2* __restrict__ H2,
                const float* __restrict__ eps, float* __restrict__ out, int N) {
    __shared__ uint2 se[CAP];
    __shared__ int lofs[BROWS + 1];
    const int b   = blockIdx.x;
    const int tid = threadIdx.x;

    if (tid <= BROWS) lofs[tid] = lofs_g[b * LOFS_STRIDE + tid];

    const int cnt = min(bcur[b], CAP);
    const uint2* eb = binned + (size_t)b * CAP;
#pragma unroll
    for (int it = 0; it < 5; ++it) {
        int j = tid + it * 1024;
        if (j < cnt) se[j] = nt_load_edge(&eb[j]);
    }
    __syncthreads();

    const int f = tid & 7;
    const int g = tid >> 3;
    float2 acc = pull_row2(se, lofs[g], lofs[g + 1], H2, f);
    float ax = acc.x, ay = acc.y;

    float zx = __shfl(ax, f >> 1, 8), zy = __shfl(ay, f >> 1, 8);
    float zm = (f & 1) ? zy : zx;
    int s = f + 7;
    float lx = __shfl(ax, s >> 1, 8), ly = __shfl(ay, s >> 1, 8);
    float ls = (s & 1) ? ly : lx;

    int row = (b << SH) + g;
    if (row < N && f < 7) {
        out[(size_t)row * 7 + f] = zm + eps[(size_t)row * 7 + f] * __expf(ls);
    }
}

extern "C" void kernel_launch(void* const* d_in, const int* in_sizes, int n_in,
                              void* d_out, int out_size, void* d_ws, size_t ws_size,
                              hipStream_t stream) {
    const float* X   = (const float*)d_in[0];
    const int*   er  = (const int*)d_in[1];
    const int*   ec  = (const int*)d_in[2];
    const float* ev  = (const float*)d_in[3];
    const float* W1  = (const float*)d_in[4];
    const float* W2  = (const float*)d_in[5];
    const float* W3  = (const float*)d_in[6];
    const float* eps = (const float*)d_in[7];
    float* out = (float*)d_out;

    const int N    = in_sizes[0] / 512;
    const int E    = in_sizes[1];
    const int nbkt = (N + BROWS - 1) >> SH;   // 782 for N=100000 (<= NBKT_MAX)

    // workspace layout (halves first, then ints, then edge records)
    __half* XW1_h = (__half*)d_ws;                        // N*16 fp16 (3.2MB)
    __half* M23_h = XW1_h + (size_t)N * 16;               // N*16 fp16 (3.2MB)
    int*    bcur  = (int*)(M23_h + (size_t)N * 16);       // pad 1024 ints
    int*    lofs_g= bcur + 1024;                          // NBKT_MAX*LOFS_STRIDE
    uint2*  binned= (uint2*)(lofs_g + NBKT_MAX * LOFS_STRIDE); // nbkt*CAP*8B

    (void)hipMemsetAsync(bcur, 0, (size_t)nbkt * sizeof(int), stream);
    k_bin     <<<BINB, 512, 0, stream>>>(er, ec, ev, bcur, binned, E, nbkt);
    k_xw1     <<<2048, 256, 0, stream>>>(X, W1, XW1_h, N);
    k_spmm_d23<<<nbkt, 1024, 0, stream>>>(binned, bcur, lofs_g,
                                          (const __half2*)XW1_h, W2, W3,
                                          (__half2*)M23_h, N);
    k_spmm_out<<<nbkt, 1024, 0, stream>>>(binned, bcur, lofs_g,
                                          (const __half2*)M23_h, eps, out, N);
}

// Round 20
// 177.082 us; speedup vs baseline: 1.8133x; 1.0006x over previous
//
#include <hip/hip_runtime.h>
#include <hip/hip_fp16.h>

// VGAE encoder forward.
// R20: exact revert to R18. R19's cooperative fusion failed because
// hipLaunchCooperativeKernel is incompatible with the harness's graph
// capture (launch error swallowed -> k_spmm_fused never ran). The
// d23->out handoff (~15us) is the price of staying capture-safe.
//
// Stages: memset bcur | k_bin | k_xw1 | k_spmm_d23 | k_spmm_out

#define SH    7              // rows per bucket = 128
#define BROWS 128
#define NBKT_MAX 800         // runtime nbkt = (N+127)>>7 = 782 for N=100000
#define CAP   4864           // bucket capacity; mean 4092 -> +12 sigma
#define LOFS_STRIDE (BROWS + 4)
#define BINB  512            // bin blocks; chunk = E/512 = 6250
#define BCHUNK 6272          // LDS staging capacity (>= chunk)
#define BSLOT 13             // ceil(6250/512) register stash slots

__device__ __forceinline__ uint2 nt_load_edge(const uint2* p) {
    unsigned long long v =
        __builtin_nontemporal_load(reinterpret_cast<const unsigned long long*>(p));
    return make_uint2((unsigned)v, (unsigned)(v >> 32));
}
__device__ __forceinline__ void nt_store_edge(uint2* p, uint2 e) {
    unsigned long long v = (unsigned long long)e.x |
                           ((unsigned long long)e.y << 32);
    __builtin_nontemporal_store(v, reinterpret_cast<unsigned long long*>(p));
}

// k_bin v4: per-block counting sort into LDS + bid[] id array, linear flush.
__global__ __launch_bounds__(512)
void k_bin(const int* __restrict__ er, const int* __restrict__ ec,
           const float* __restrict__ ev, int* __restrict__ bcur,
           uint2* __restrict__ binned, int E, int nbkt) {
    __shared__ uint2 buf[BCHUNK];                // 50.2 KB sorted stage
    __shared__ unsigned short bid[BCHUNK];       // 12.5 KB bucket ids
    __shared__ int lofs[NBKT_MAX + 1];
    __shared__ int lcnt[NBKT_MAX];
    __shared__ int gbase[NBKT_MAX];
    const int tid = threadIdx.x;
    const int chunk = (E + BINB - 1) / BINB;
    const int lo = blockIdx.x * chunk;
    const int hi = min(lo + chunk, E);
    const int cnt_tile = hi - lo;

    for (int t = tid; t < nbkt; t += 512) lcnt[t] = 0;
    __syncthreads();

    // pass 1: load (nt), stash in regs, hist
    uint2 st[BSLOT]; int sb[BSLOT];
#pragma unroll
    for (int it = 0; it < BSLOT; ++it) {
        int e = lo + tid + it * 512;
        if (e < hi) {
            int r = __builtin_nontemporal_load(&er[e]);
            int c = __builtin_nontemporal_load(&ec[e]);
            float v = __builtin_nontemporal_load(&ev[e]);
            int b = r >> SH;
            st[it] = make_uint2(((unsigned)(r & (BROWS - 1)) << 17) | (unsigned)c,
                                __float_as_uint(v));
            sb[it] = b;
            atomicAdd(&lcnt[b], 1);
        } else sb[it] = -1;
    }
    __syncthreads();

    // inclusive scan lcnt -> lofs[1..nbkt], lofs[0] = 0
    for (int t = tid; t < nbkt; t += 512) lofs[t + 1] = lcnt[t];
    if (tid == 0) lofs[0] = 0;
    __syncthreads();
    for (int off = 1; off < nbkt; off <<= 1) {
        int i0 = tid, i1 = tid + 512;
        int v0 = (i0 < nbkt && i0 >= off) ? lofs[i0 + 1 - off] : 0;
        int v1 = (i1 < nbkt && i1 >= off) ? lofs[i1 + 1 - off] : 0;
        __syncthreads();
        if (i0 < nbkt) lofs[i0 + 1] += v0;
        if (i1 < nbkt) lofs[i1 + 1] += v1;
        __syncthreads();
    }

    // reserve global ranges; reset lcnt for placement ranks
    for (int t = tid; t < nbkt; t += 512) {
        int n = lofs[t + 1] - lofs[t];
        gbase[t] = n ? atomicAdd(&bcur[t], n) : 0;
        lcnt[t] = 0;
    }
    __syncthreads();

    // pass 2: place stash into sorted LDS positions (+ record bucket id)
#pragma unroll
    for (int it = 0; it < BSLOT; ++it) {
        if (sb[it] >= 0) {
            int pos = lofs[sb[it]] + atomicAdd(&lcnt[sb[it]], 1);
            buf[pos] = st[it];
            bid[pos] = (unsigned short)sb[it];
        }
    }
    __syncthreads();

    // flush: consecutive threads -> consecutive global addresses per bucket
    for (int i = tid; i < cnt_tile; i += 512) {
        uint2 rec = buf[i];
        int b = bid[i];
        int gpos = gbase[b] + (i - lofs[b]);
        if (gpos < CAP) binned[(size_t)b * CAP + gpos] = rec;
    }
}

// XW1 = X @ W1, fp16 out. Row-pair per wave with next-pair prefetch.
__global__ __launch_bounds__(256, 2)
void k_xw1(const float* __restrict__ X, const float* __restrict__ W1,
           __half* __restrict__ out, int N) {
    const int lane = threadIdx.x & 63;
    const int wave  = (blockIdx.x * blockDim.x + threadIdx.x) >> 6;
    const int nwave = (gridDim.x * blockDim.x) >> 6;
    const int step  = nwave * 2;

    float w[8][16];
#pragma unroll
    for (int j = 0; j < 4; ++j) {
#pragma unroll
        for (int h4 = 0; h4 < 4; ++h4) {
            float4 a = *reinterpret_cast<const float4*>(W1 + (lane * 4 + j) * 16 + h4 * 4);
            w[j][h4*4+0] = a.x; w[j][h4*4+1] = a.y; w[j][h4*4+2] = a.z; w[j][h4*4+3] = a.w;
            float4 b = *reinterpret_cast<const float4*>(W1 + (256 + lane * 4 + j) * 16 + h4 * 4);
            w[4+j][h4*4+0] = b.x; w[4+j][h4*4+1] = b.y; w[4+j][h4*4+2] = b.z; w[4+j][h4*4+3] = b.w;
        }
    }

    const int l4 = lane & 15;
    const int hrev = ((l4 & 1) << 3) | ((l4 & 2) << 1) | ((l4 & 4) >> 1) | ((l4 & 8) >> 3);

    const float4* X4 = reinterpret_cast<const float4*>(X);

    int row = wave * 2;
    if (row >= N) return;
    int r1 = min(row + 1, N - 1);
    float4 xa0 = X4[(size_t)row * 128 + lane];
    float4 xb0 = X4[(size_t)row * 128 + 64 + lane];
    float4 xa1 = X4[(size_t)r1 * 128 + lane];
    float4 xb1 = X4[(size_t)r1 * 128 + 64 + lane];

    for (; row < N; row += step) {
        int nr = row + step;
        float4 na0, nb0, na1, nb1;
        if (nr < N) {
            int nr1 = min(nr + 1, N - 1);
            na0 = X4[(size_t)nr * 128 + lane];
            nb0 = X4[(size_t)nr * 128 + 64 + lane];
            na1 = X4[(size_t)nr1 * 128 + lane];
            nb1 = X4[(size_t)nr1 * 128 + 64 + lane];
        }

        float a0[16], a1[16];
#pragma unroll
        for (int h = 0; h < 16; ++h) {
            a0[h] = xa0.x * w[0][h] + xa0.y * w[1][h] + xa0.z * w[2][h] + xa0.w * w[3][h]
                  + xb0.x * w[4][h] + xb0.y * w[5][h] + xb0.z * w[6][h] + xb0.w * w[7][h];
            a1[h] = xa1.x * w[0][h] + xa1.y * w[1][h] + xa1.z * w[2][h] + xa1.w * w[3][h]
                  + xb1.x * w[4][h] + xb1.y * w[5][h] + xb1.z * w[6][h] + xb1.w * w[7][h];
        }

#define XW1_STEP(arr, m, half_)                                            \
        {                                                                  \
            const bool hi_ = (lane & (m)) != 0;                            \
            _Pragma("unroll")                                              \
            for (int i = 0; i < (half_); ++i) {                            \
                float send = hi_ ? arr[i] : arr[(half_) + i];              \
                float keep = hi_ ? arr[(half_) + i] : arr[i];              \
                arr[i] = keep + __shfl_xor(send, (m));                     \
            }                                                              \
        }
        XW1_STEP(a0, 1, 8) XW1_STEP(a0, 2, 4) XW1_STEP(a0, 4, 2) XW1_STEP(a0, 8, 1)
        a0[0] += __shfl_xor(a0[0], 16);
        a0[0] += __shfl_xor(a0[0], 32);
        XW1_STEP(a1, 1, 8) XW1_STEP(a1, 2, 4) XW1_STEP(a1, 4, 2) XW1_STEP(a1, 8, 1)
        a1[0] += __shfl_xor(a1[0], 16);
        a1[0] += __shfl_xor(a1[0], 32);
#undef XW1_STEP

        if (lane < 16) {
            out[(size_t)row * 16 + hrev] = __float2half(a0[0]);
            if (row + 1 < N) out[(size_t)(row + 1) * 16 + hrev] = __float2half(a1[0]);
        }

        xa0 = na0; xb0 = nb0; xa1 = na1; xb1 = nb1;
    }
}

// half2 pull body: lane f gathers features {2f,2f+1}; 4-deep MLP.
__device__ __forceinline__ float2 pull_row2(const uint2* __restrict__ se,
                                            int beg, int end,
                                            const __half2* __restrict__ H2, int f) {
    float x0=0.f,y0=0.f,x1=0.f,y1=0.f,x2=0.f,y2=0.f,x3=0.f,y3=0.f;
    int j = beg;
    for (; j + 4 <= end; j += 4) {
        uint2 e0 = se[j], e1 = se[j+1], e2 = se[j+2], e3 = se[j+3];
        float2 h0 = __half22float2(H2[(size_t)(e0.x & 0x1FFFF) * 8 + f]);
        float2 h1 = __half22float2(H2[(size_t)(e1.x & 0x1FFFF) * 8 + f]);
        float2 h2 = __half22float2(H2[(size_t)(e2.x & 0x1FFFF) * 8 + f]);
        float2 h3 = __half22float2(H2[(size_t)(e3.x & 0x1FFFF) * 8 + f]);
        float v0 = __uint_as_float(e0.y), v1 = __uint_as_float(e1.y);
        float v2 = __uint_as_float(e2.y), v3 = __uint_as_float(e3.y);
        x0 += v0 * h0.x; y0 += v0 * h0.y;
        x1 += v1 * h1.x; y1 += v1 * h1.y;
        x2 += v2 * h2.x; y2 += v2 * h2.y;
        x3 += v3 * h3.x; y3 += v3 * h3.y;
    }
    for (; j < end; ++j) {
        uint2 e = se[j];
        float2 h = __half22float2(H2[(size_t)(e.x & 0x1FFFF) * 8 + f]);
        float v = __uint_as_float(e.y);
        x0 += v * h.x; y0 += v * h.y;
    }
    return make_float2((x0 + x1) + (x2 + x3), (y0 + y1) + (y2 + y3));
}

// Bucket SpMM (sort + half2 pull) + relu+[W2|W3] epilogue (half2 M out).
__global__ __launch_bounds__(1024)
void k_spmm_d23(uint2* __restrict__ binned, const int* __restrict__ bcur,
                int* __restrict__ lofs_g, const __half2* __restrict__ H2,
                const float* __restrict__ W2, const float* __restrict__ W3,
                __half2* __restrict__ M2, int N) {
    __shared__ uint2 se[CAP];
    __shared__ int lhist[4][BROWS];     // 4-way replicated hist
    __shared__ int lofs[BROWS + 1];
    __shared__ int lrank[BROWS];
    const int b   = blockIdx.x;
    const int tid = threadIdx.x;
    const int rep = tid & 3;

    if (tid < BROWS) {
        lhist[0][tid] = 0; lhist[1][tid] = 0;
        lhist[2][tid] = 0; lhist[3][tid] = 0;
        lrank[tid] = 0;
    }
    __syncthreads();

    const int cnt = min(bcur[b], CAP);
    const uint2* eb = binned + (size_t)b * CAP;

    uint2 st[5]; int slr[5];
#pragma unroll
    for (int it = 0; it < 5; ++it) {
        int j = tid + it * 1024;
        if (j < cnt) {
            uint2 e = nt_load_edge(&eb[j]);
            st[it] = e;
            slr[it] = (int)(e.x >> 17);
            atomicAdd(&lhist[rep][slr[it]], 1);
        } else slr[it] = -1;
    }
    __syncthreads();

    if (tid < BROWS)
        lofs[tid + 1] = lhist[0][tid] + lhist[1][tid] + lhist[2][tid] + lhist[3][tid];
    if (tid == 0) lofs[0] = 0;
    __syncthreads();
    for (int off = 1; off < BROWS; off <<= 1) {
        int v = (tid < BROWS && tid >= off) ? lofs[tid + 1 - off] : 0;
        __syncthreads();
        if (tid < BROWS) lofs[tid + 1] += v;
        __syncthreads();
    }

#pragma unroll
    for (int it = 0; it < 5; ++it) {
        if (slr[it] >= 0) {
            int pos = lofs[slr[it]] + atomicAdd(&lrank[slr[it]], 1);
            se[pos] = st[it];
        }
    }
    __syncthreads();

    // persist sorted bucket + offsets for k_spmm_out
    uint2* wb = binned + (size_t)b * CAP;
#pragma unroll
    for (int it = 0; it < 5; ++it) {
        int j = tid + it * 1024;
        if (j < cnt) nt_store_edge(&wb[j], se[j]);
    }
    if (tid <= BROWS) lofs_g[b * LOFS_STRIDE + tid] = lofs[tid];

    // half2 pull: 128 groups of 8 lanes, group = local row
    const int f = tid & 7;      // feature pair {2f, 2f+1}
    const int g = tid >> 3;     // local row
    const int j0 = 2 * f, j1 = 2 * f + 1;
    float wA[16], wB[16];
#pragma unroll
    for (int k = 0; k < 16; ++k) {
        wA[k] = (j0 < 7) ? W2[k * 7 + j0] : (j0 < 14 ? W3[k * 7 + (j0 - 7)] : 0.f);
        wB[k] = (j1 < 7) ? W2[k * 7 + j1] : (j1 < 14 ? W3[k * 7 + (j1 - 7)] : 0.f);
    }
    float2 acc = pull_row2(se, lofs[g], lofs[g + 1], H2, f);
    float ax = fmaxf(acc.x, 0.f), ay = fmaxf(acc.y, 0.f);
    float oA = 0.f, oB = 0.f;
#pragma unroll
    for (int s = 0; s < 8; ++s) {
        float rx = __shfl(ax, s, 8);
        float ry = __shfl(ay, s, 8);
        oA += rx * wA[2*s] + ry * wA[2*s + 1];
        oB += rx * wB[2*s] + ry * wB[2*s + 1];
    }
    int row = (b << SH) + g;
    if (row < N) M2[(size_t)row * 8 + f] = __floats2half2_rn(oA, oB);
}

// Bucket SpMM (pre-sorted: copy + half2 pull) + reparameterization.
__global__ __launch_bounds__(1024)
void k_spmm_out(const uint2* __restrict__ binned, const int* __restrict__ bcur,
                const int* __restrict__ lofs_g, const __half2* __restrict__ H2,
                const float* __restrict__ eps, float* __restrict__ out, int N) {
    __shared__ uint2 se[CAP];
    __shared__ int lofs[BROWS + 1];
    const int b   = blockIdx.x;
    const int tid = threadIdx.x;

    if (tid <= BROWS) lofs[tid] = lofs_g[b * LOFS_STRIDE + tid];

    const int cnt = min(bcur[b], CAP);
    const uint2* eb = binned + (size_t)b * CAP;
#pragma unroll
    for (int it = 0; it < 5; ++it) {
        int j = tid + it * 1024;
        if (j < cnt) se[j] = nt_load_edge(&eb[j]);
    }
    __syncthreads();

    const int f = tid & 7;
    const int g = tid >> 3;
    float2 acc = pull_row2(se, lofs[g], lofs[g + 1], H2, f);
    float ax = acc.x, ay = acc.y;

    float zx = __shfl(ax, f >> 1, 8), zy = __shfl(ay, f >> 1, 8);
    float zm = (f & 1) ? zy : zx;
    int s = f + 7;
    float lx = __shfl(ax, s >> 1, 8), ly = __shfl(ay, s >> 1, 8);
    float ls = (s & 1) ? ly : lx;

    int row = (b << SH) + g;
    if (row < N && f < 7) {
        out[(size_t)row * 7 + f] = zm + eps[(size_t)row * 7 + f] * __expf(ls);
    }
}

extern "C" void kernel_launch(void* const* d_in, const int* in_sizes, int n_in,
                              void* d_out, int out_size, void* d_ws, size_t ws_size,
                              hipStream_t stream) {
    const float* X   = (const float*)d_in[0];
    const int*   er  = (const int*)d_in[1];
    const int*   ec  = (const int*)d_in[2];
    const float* ev  = (const float*)d_in[3];
    const float* W1  = (const float*)d_in[4];
    const float* W2  = (const float*)d_in[5];
    const float* W3  = (const float*)d_in[6];
    const float* eps = (const float*)d_in[7];
    float* out = (float*)d_out;

    const int N    = in_sizes[0] / 512;
    const int E    = in_sizes[1];
    const int nbkt = (N + BROWS - 1) >> SH;   // 782 for N=100000 (<= NBKT_MAX)

    // workspace layout (halves first, then ints, then edge records)
    __half* XW1_h = (__half*)d_ws;                        // N*16 fp16 (3.2MB)
    __half* M23_h = XW1_h + (size_t)N * 16;               // N*16 fp16 (3.2MB)
    int*    bcur  = (int*)(M23_h + (size_t)N * 16);       // pad 1024 ints
    int*    lofs_g= bcur + 1024;                          // NBKT_MAX*LOFS_STRIDE
    uint2*  binned= (uint2*)(lofs_g + NBKT_MAX * LOFS_STRIDE); // nbkt*CAP*8B

    (void)hipMemsetAsync(bcur, 0, (size_t)nbkt * sizeof(int), stream);
    k_bin     <<<BINB, 512, 0, stream>>>(er, ec, ev, bcur, binned, E, nbkt);
    k_xw1     <<<2048, 256, 0, stream>>>(X, W1, XW1_h, N);
    k_spmm_d23<<<nbkt, 1024, 0, stream>>>(binned, bcur, lofs_g,
                                          (const __half2*)XW1_h, W2, W3,
                                          (__half2*)M23_h, N);
    k_spmm_out<<<nbkt, 1024, 0, stream>>>(binned, bcur, lofs_g,
                                          (const __half2*)M23_h, eps, out, N);
}